// Round 1
// baseline (1599.796 us; speedup 1.0000x reference)
//
#include <hip/hip_runtime.h>
#include <math.h>

#define B_ 32
#define T_ 4096
#define D_ 256
#define C_ 64
#define NB_ 17
#define EPSN 1e-6f
#define EPSG 1e-6f
#define EPSL 1e-5f
#define DS_ 0.1f

// ================= Kernel A: normalize + banded strip =================
// grid: 2 * B_ * (T_/TS); block 256. mod0 = audio, mod1 = video.
#define TS 32
#define HALO 8
#define ROWS (TS + HALO)   // 40
#define TPAD 41            // stride coprime with 32 -> conflict-free

__global__ __launch_bounds__(256) void strip_kernel(
    const float* __restrict__ feat0, const float* __restrict__ mask0,
    const float* __restrict__ feat1, const float* __restrict__ mask1,
    float* __restrict__ s_out)      // [2][B][9][T]
{
    __shared__ float xT[D_ * TPAD];          // [d][r] transposed tile
    __shared__ float part[8 * TS * 9];       // [dq][t][a] partial dots
    __shared__ float nrm[ROWS], scl[ROWS], msk[ROWS];

    const int NTILE = T_ / TS;               // 128
    int bid  = blockIdx.x;
    int tile = bid % NTILE;
    int b    = (bid / NTILE) % B_;
    int mod  = bid / (NTILE * B_);
    const float* feat = mod ? feat1 : feat0;
    const float* mask = mod ? mask1 : mask0;
    int t0 = tile * TS;
    int tid = threadIdx.x;
    int lane = tid & 63;
    int wq = tid >> 6;

    // load tile transposed: lane indexes d (coalesced global, conflict-free LDS: stride 41)
    for (int r = wq; r < ROWS; r += 4) {
        int tg = t0 + r;
        bool inb = (tg < T_);
        const float* src = feat + ((size_t)b * T_ + (inb ? tg : 0)) * D_;
        for (int db = 0; db < D_; db += 64) {
            float v = inb ? src[db + lane] : 0.0f;
            xT[(db + lane) * TPAD + r] = v;
        }
    }
    if (tid < ROWS) {
        int tg = t0 + tid;
        msk[tid] = (tg < T_) ? mask[(size_t)b * T_ + tg] : 0.0f;
    }
    __syncthreads();

    // norms (threads 0..ROWS-1)
    if (tid < ROWS) {
        float ss = 0.f;
        for (int d = 0; d < D_; ++d) { float v = xT[d * TPAD + tid]; ss += v * v; }
        float n  = sqrtf(ss);
        float m  = msk[tid];
        float nm = m * n;                 // ||x*m||
        nrm[tid] = nm;
        scl[tid] = m / (nm + EPSN);       // xn = x * scl
    }
    __syncthreads();

    // raw dot partials: thread = (t = tid%32, dq = tid/32), d-range of 32
    {
        int t  = tid & 31;
        int dq = tid >> 5;
        float acc[8];
        #pragma unroll
        for (int a = 0; a < 8; ++a) acc[a] = 0.f;
        for (int d = dq * 32; d < dq * 32 + 32; ++d) {
            const float* row = xT + d * TPAD;
            float v0 = row[t];
            #pragma unroll
            for (int a = 1; a <= 8; ++a) acc[a - 1] += v0 * row[t + a];
        }
        #pragma unroll
        for (int a = 0; a < 8; ++a) part[(dq * TS + t) * 9 + a] = acc[a];
    }
    __syncthreads();

    if (tid < TS) {
        int t = tid;
        float m_t = msk[t];
        size_t obase = (((size_t)mod * B_ + b) * 9) * T_ + (t0 + t);
        // a = 0 band from norm: dot = (nm/(nm+eps))^2
        float nm = nrm[t];
        float r0 = nm / (nm + EPSN);
        s_out[obase] = (r0 * r0 - DS_ + 1.0f) * 0.5f * m_t * m_t;
        #pragma unroll
        for (int a = 1; a <= 8; ++a) {
            float dsum = 0.f;
            #pragma unroll
            for (int dq = 0; dq < 8; ++dq) dsum += part[(dq * TS + t) * 9 + (a - 1)];
            float dn = dsum * scl[t] * scl[t + a];
            float sa = (dn + 1.0f) * 0.5f * m_t * msk[t + a];
            if (t0 + t + a >= T_) sa = 0.f;       // jnp.pad zeros at the end
            s_out[obase + (size_t)a * T_] = sa;
        }
    }
}

// ================= Kernel B: conv stack + masked GAP partials =================
#define TT 128
#define WCOLS 142          // TT + 2*7 halo
#define WP 145             // row stride, coprime with 32
#define JB 8

template<int DIL>
__device__ inline void do_stage(float* __restrict__ bufIN, float* __restrict__ bufTMP,
    float* __restrict__ wcv, float* __restrict__ wpw,
    const float* __restrict__ w_d, const float* __restrict__ b_d,
    const float* __restrict__ w_p, const float* __restrict__ b_p,
    int jlo, int jhi, int t0, int c, int wq, int tid)
{
    // stage weights -> LDS, lane-major layouts: wcv[(ci*3+tap)*64 + c], wpw[ci*64 + c]
    for (int idx = tid; idx < 64 * 64 * 3; idx += 256) {
        int cc = idx & 63; int m3 = idx >> 6;
        int ci = m3 / 3;   int tap = m3 - 3 * ci;
        wcv[idx] = w_d[cc * 192 + ci * 3 + tap];
    }
    for (int idx = tid; idx < 64 * 64; idx += 256) {
        int cc = idx & 63; int ci = idx >> 6;
        wpw[idx] = w_p[cc * 64 + ci];
    }
    float bd = b_d[c], bp = b_p[c];
    __syncthreads();

    // dilated 3-tap conv: bufIN -> bufTMP over [jlo, jhi)
    for (int jb = jlo + wq * JB; jb < jhi; jb += 4 * JB) {
        float acc[JB];
        #pragma unroll
        for (int k = 0; k < JB; ++k) acc[k] = bd;
        for (int ci = 0; ci < 64; ++ci) {
            const float* row = bufIN + ci * WP + jb - DIL;
            float w0 = wcv[(ci * 3 + 0) * 64 + c];
            float w1 = wcv[(ci * 3 + 1) * 64 + c];
            float w2 = wcv[(ci * 3 + 2) * 64 + c];
            float xv[JB + 2 * DIL];
            #pragma unroll
            for (int q = 0; q < JB + 2 * DIL; ++q) xv[q] = row[q];   // broadcast reads
            #pragma unroll
            for (int k = 0; k < JB; ++k)
                acc[k] += w0 * xv[k] + w1 * xv[k + DIL] + w2 * xv[k + 2 * DIL];
        }
        #pragma unroll
        for (int k = 0; k < JB; ++k) {
            int j = jb + k;
            if (j < jhi) {
                int tg = t0 - 7 + j;
                bufTMP[c * WP + j] = (tg >= 0 && tg < T_) ? fmaxf(acc[k], 0.f) : 0.f;
            }
        }
    }
    __syncthreads();

    // pointwise conv: bufTMP -> bufIN over [jlo, jhi)
    for (int jb = jlo + wq * JB; jb < jhi; jb += 4 * JB) {
        float acc[JB];
        #pragma unroll
        for (int k = 0; k < JB; ++k) acc[k] = bp;
        for (int ci = 0; ci < 64; ++ci) {
            const float* row = bufTMP + ci * WP + jb;
            float w0 = wpw[ci * 64 + c];
            float xv[JB];
            #pragma unroll
            for (int q = 0; q < JB; ++q) xv[q] = row[q];
            #pragma unroll
            for (int k = 0; k < JB; ++k) acc[k] += w0 * xv[k];
        }
        #pragma unroll
        for (int k = 0; k < JB; ++k) {
            int j = jb + k;
            if (j < jhi) {
                int tg = t0 - 7 + j;
                bufIN[c * WP + j] = (tg >= 0 && tg < T_) ? fmaxf(acc[k], 0.f) : 0.f;
            }
        }
    }
    __syncthreads();
}

__global__ __launch_bounds__(256) void conv_kernel(
    const float* __restrict__ s_in,     // [2][B][9][T]
    const float* __restrict__ mask0, const float* __restrict__ mask1,
    const float* __restrict__ w_in, const float* __restrict__ b_in,
    const float* __restrict__ w_d1, const float* __restrict__ b_d1,
    const float* __restrict__ w_p1, const float* __restrict__ b_p1,
    const float* __restrict__ w_d2, const float* __restrict__ b_d2,
    const float* __restrict__ w_p2, const float* __restrict__ b_p2,
    const float* __restrict__ w_d3, const float* __restrict__ b_d3,
    const float* __restrict__ w_p3, const float* __restrict__ b_p3,
    float* __restrict__ z_part)         // [2][B][NTILE][64]
{
    extern __shared__ float sm[];
    float* bufA  = sm;                     // [64][WP]
    float* bufB  = bufA + 64 * WP;         // [64][WP]
    float* stile = bufB + 64 * WP;         // [9][WCOLS]
    float* weff  = stile + 9 * WCOLS;      // [9][64]
    float* wcv   = weff + 9 * 64;          // [192][64]
    float* wpw   = wcv + 192 * 64;         // [64][64]
    float* mld   = wpw + 64 * 64;          // [TT]
    float* part  = mld + TT;               // [4][64]  (+16 slack floats after)

    const int NTILE = T_ / TT;             // 32
    int bid  = blockIdx.x;
    int tile = bid % NTILE;
    int b    = (bid / NTILE) % B_;
    int mod  = bid / (NTILE * B_);
    const float* mask = mod ? mask1 : mask0;
    int t0  = tile * TT;
    int tid = threadIdx.x;
    int c   = tid & 63;
    int wq  = tid >> 6;

    for (int idx = tid; idx < 9 * WCOLS; idx += 256) {
        int a = idx / WCOLS, j = idx - a * WCOLS;
        int tg = t0 - 7 + j;
        float v = 0.f;
        if (tg >= 0 && tg < T_) v = s_in[(((size_t)mod * B_ + b) * 9 + a) * T_ + tg];
        stile[a * WCOLS + j] = v;
    }
    if (tid < TT) mld[tid] = mask[(size_t)b * T_ + t0 + tid];
    if (tid < 64) {
        #pragma unroll
        for (int a = 0; a < 9; ++a) {
            float w = w_in[tid * NB_ + 8 + a];
            if (a > 0) w += w_in[tid * NB_ + 8 - a];
            weff[a * 64 + tid] = w;
        }
    }
    float bin = b_in[c];
    __syncthreads();

    // h0 (1x1 conv over 9 folded bands) -> bufA, all WCOLS cols
    for (int j = wq; j < WCOLS; j += 4) {
        float acc = bin;
        #pragma unroll
        for (int a = 0; a < 9; ++a) acc += weff[a * 64 + c] * stile[a * WCOLS + j];
        int tg = t0 - 7 + j;
        bufA[c * WP + j] = (tg >= 0 && tg < T_) ? fmaxf(acc, 0.f) : 0.f;
    }
    __syncthreads();

    do_stage<1>(bufA, bufB, wcv, wpw, w_d1, b_d1, w_p1, b_p1, 1, 141, t0, c, wq, tid);
    do_stage<2>(bufA, bufB, wcv, wpw, w_d2, b_d2, w_p2, b_p2, 3, 139, t0, c, wq, tid);
    do_stage<4>(bufA, bufB, wcv, wpw, w_d3, b_d3, w_p3, b_p3, 7, 135, t0, c, wq, tid);

    // masked GAP partial over this tile's 128 cols [7,135)
    {
        float acc = 0.f;
        #pragma unroll 4
        for (int k = 0; k < 32; ++k) {
            int j = 7 + wq * 32 + k;
            acc += bufA[c * WP + j] * mld[j - 7];
        }
        part[wq * 64 + c] = acc;
    }
    __syncthreads();
    if (tid < 64) {
        float z = part[tid] + part[64 + tid] + part[128 + tid] + part[192 + tid];
        z_part[(((size_t)mod * B_ + b) * NTILE + tile) * 64 + tid] = z;
    }
}

// ================= Kernel C: GAP divide + LayerNorm + gates =================
__global__ __launch_bounds__(128) void gates_kernel(
    const float* __restrict__ z_part,
    const float* __restrict__ mask0, const float* __restrict__ mask1,
    const float* __restrict__ ln_g, const float* __restrict__ ln_b,
    const float* __restrict__ mha_w1, const float* __restrict__ mha_b1,
    const float* __restrict__ mha_w2, const float* __restrict__ mha_b2,
    const float* __restrict__ ffn_w1, const float* __restrict__ ffn_b1,
    const float* __restrict__ ffn_w2, const float* __restrict__ ffn_b2,
    float* __restrict__ out)
{
    __shared__ float fn[128];
    __shared__ float red[4];
    __shared__ float msum[2];
    const int NTILE = T_ / TT;
    int b = blockIdx.x, tid = threadIdx.x;
    int mod = tid >> 6, c = tid & 63;    // mod0: f[0:64]=z_audio, mod1: f[64:128]=z_video

    float z = 0.f;
    for (int tl = 0; tl < NTILE; ++tl)
        z += z_part[(((size_t)mod * B_ + b) * NTILE + tl) * 64 + c];

    const float* mk = mod ? mask1 : mask0;
    float ms = 0.f;
    for (int t = c; t < T_; t += 64) ms += mk[(size_t)b * T_ + t];
    #pragma unroll
    for (int o = 32; o > 0; o >>= 1) ms += __shfl_xor(ms, o);
    if (c == 0) msum[mod] = ms;
    __syncthreads();

    float fv = z / (msum[mod] + EPSG);
    float s1 = fv, s2 = fv * fv;
    #pragma unroll
    for (int o = 32; o > 0; o >>= 1) { s1 += __shfl_xor(s1, o); s2 += __shfl_xor(s2, o); }
    if (c == 0) { red[mod * 2] = s1; red[mod * 2 + 1] = s2; }
    __syncthreads();

    float mu  = (red[0] + red[2]) * (1.0f / 128.0f);
    float ex2 = (red[1] + red[3]) * (1.0f / 128.0f);
    float var = ex2 - mu * mu;
    float fnv = (fv - mu) * rsqrtf(var + EPSL) * ln_g[tid] + ln_b[tid];
    fn[tid] = fnv;
    __syncthreads();

    const float* W1 = mod ? ffn_w1 : mha_w1;
    const float* B1 = mod ? ffn_b1 : mha_b1;
    const float* W2 = mod ? ffn_w2 : mha_w2;
    const float* B2 = mod ? ffn_b2 : mha_b2;
    float r = B1[c];
    for (int i = 0; i < 128; ++i) r += fn[i] * W1[i * 64 + c];
    r = fmaxf(r, 0.f);
    float g = r * W2[c];
    #pragma unroll
    for (int o = 32; o > 0; o >>= 1) g += __shfl_xor(g, o);
    if (c == 0) {
        g += B2[0];
        out[mod * B_ + b] = mod ? tanhf(g) : 1.0f / (1.0f + expf(-g));
    }
}

// ================= launch =================
extern "C" void kernel_launch(void* const* d_in, const int* in_sizes, int n_in,
                              void* d_out, int out_size, void* d_ws, size_t ws_size,
                              hipStream_t stream) {
    const float* video_feat = (const float*)d_in[0];
    const float* audio_feat = (const float*)d_in[1];
    const float* video_mask = (const float*)d_in[2];
    const float* audio_mask = (const float*)d_in[3];
    const float* w_in = (const float*)d_in[4];
    const float* b_in = (const float*)d_in[5];
    const float* w_d1 = (const float*)d_in[6];
    const float* b_d1 = (const float*)d_in[7];
    const float* w_p1 = (const float*)d_in[8];
    const float* b_p1 = (const float*)d_in[9];
    const float* w_d2 = (const float*)d_in[10];
    const float* b_d2 = (const float*)d_in[11];
    const float* w_p2 = (const float*)d_in[12];
    const float* b_p2 = (const float*)d_in[13];
    const float* w_d3 = (const float*)d_in[14];
    const float* b_d3 = (const float*)d_in[15];
    const float* w_p3 = (const float*)d_in[16];
    const float* b_p3 = (const float*)d_in[17];
    const float* ln_g = (const float*)d_in[18];
    const float* ln_b = (const float*)d_in[19];
    const float* mha_w1 = (const float*)d_in[20];
    const float* mha_b1 = (const float*)d_in[21];
    const float* mha_w2 = (const float*)d_in[22];
    const float* mha_b2 = (const float*)d_in[23];
    const float* ffn_w1 = (const float*)d_in[24];
    const float* ffn_b1 = (const float*)d_in[25];
    const float* ffn_w2 = (const float*)d_in[26];
    const float* ffn_b2 = (const float*)d_in[27];

    float* s_buf  = (float*)d_ws;                          // 2*B*9*T
    float* z_part = s_buf + (size_t)2 * B_ * 9 * T_;       // 2*B*(T/TT)*64

    strip_kernel<<<dim3(2 * B_ * (T_ / TS)), dim3(256), 0, stream>>>(
        audio_feat, audio_mask, video_feat, video_mask, s_buf);

    size_t smB = (size_t)(2 * 64 * WP + 9 * WCOLS + 9 * 64 + 192 * 64 + 64 * 64 + TT + 4 * 64 + 16) * sizeof(float);
    hipFuncSetAttribute((const void*)conv_kernel, hipFuncAttributeMaxDynamicSharedMemorySize, (int)smB);
    conv_kernel<<<dim3(2 * B_ * (T_ / TT)), dim3(256), smB, stream>>>(
        s_buf, audio_mask, video_mask,
        w_in, b_in, w_d1, b_d1, w_p1, b_p1, w_d2, b_d2, w_p2, b_p2,
        w_d3, b_d3, w_p3, b_p3, z_part);

    gates_kernel<<<dim3(B_), dim3(128), 0, stream>>>(
        z_part, audio_mask, video_mask, ln_g, ln_b,
        mha_w1, mha_b1, mha_w2, mha_b2, ffn_w1, ffn_b1, ffn_w2, ffn_b2,
        (float*)d_out);
}

// Round 2
// 313.170 us; speedup vs baseline: 5.1084x; 5.1084x over previous
//
#include <hip/hip_runtime.h>
#include <math.h>

#define B_ 32
#define T_ 4096
#define D_ 256
#define C_ 64
#define EPSN 1e-6f
#define EPSG 1e-6f
#define EPSL 1e-5f
#define DS_ 0.1f

typedef short bfrag __attribute__((ext_vector_type(8)));      // 8 bf16 = 4 VGPR
typedef float f32x4 __attribute__((ext_vector_type(4)));
typedef unsigned short ushort4_t __attribute__((ext_vector_type(4)));
typedef unsigned short ushort8_t __attribute__((ext_vector_type(8)));

static __device__ __forceinline__ unsigned short f2bf(float f) {
    unsigned int u = __builtin_bit_cast(unsigned int, f);
    unsigned int r = u + 0x7fffu + ((u >> 16) & 1u);
    return (unsigned short)(r >> 16);
}
static __device__ __forceinline__ float bf2f(unsigned short u) {
    return __builtin_bit_cast(float, ((unsigned int)u) << 16);
}

// ===================== Kernel A: normalize + banded strip -> s16 (bf16 [mb][t][16]) =====================
#define TS 32
#define RROWS 40
#define XP 260          // f32 pitch: 16B-aligned rows, dword-bank conflict-free for float4 reads

__global__ __launch_bounds__(256, 3) void strip_kernel(
    const float* __restrict__ feat0, const float* __restrict__ mask0,
    const float* __restrict__ feat1, const float* __restrict__ mask1,
    unsigned short* __restrict__ s16g)     // [2*B][T][16] bf16, slots 0..8 = bands, 9..15 = 0
{
    __shared__ float x[RROWS * XP];
    __shared__ float part[8 * 264];
    __shared__ float sb[9 * 33];
    __shared__ float nrm[RROWS], scl[RROWS], msk[RROWS];

    int bid  = blockIdx.x;
    int tile = bid & 127;            // T_/TS = 128
    int b    = (bid >> 7) & 31;
    int mod  = bid >> 12;
    const float* feat = mod ? feat1 : feat0;
    const float* mask = mod ? mask1 : mask0;
    int t0 = tile * TS;
    int tid = threadIdx.x;
    int w = tid >> 6, lane = tid & 63;

    for (int r = w; r < RROWS; r += 4) {
        int tg = t0 + r;
        float4 v = make_float4(0.f, 0.f, 0.f, 0.f);
        if (tg < T_) v = *(const float4*)(feat + ((size_t)b * T_ + tg) * D_ + lane * 4);
        *(float4*)(x + r * XP + lane * 4) = v;
    }
    if (tid < RROWS) {
        int tg = t0 + tid;
        msk[tid] = (tg < T_) ? mask[(size_t)b * T_ + tg] : 0.f;
    }
    __syncthreads();

    if (tid < 160) {
        int r = tid >> 2, q = tid & 3;
        const float* xr = x + r * XP + q * 64;
        float ss = 0.f;
        #pragma unroll
        for (int i = 0; i < 16; ++i) {
            float4 v = *(const float4*)(xr + i * 4);
            ss += v.x * v.x + v.y * v.y + v.z * v.z + v.w * v.w;
        }
        ss += __shfl_xor(ss, 1);
        ss += __shfl_xor(ss, 2);
        if (q == 0) {
            float n = sqrtf(ss);
            float m = msk[r];
            float nm = m * n;
            nrm[r] = nm;
            scl[r] = m / (nm + EPSN);
        }
    }
    __syncthreads();

    {   // banded raw dots, d-chunked: thread = (t, dq)
        int t = tid & 31, dq = tid >> 5;
        float4 v0[8];
        const float* xrow = x + t * XP + dq * 32;
        #pragma unroll
        for (int i = 0; i < 8; ++i) v0[i] = *(const float4*)(xrow + i * 4);
        #pragma unroll
        for (int a = 1; a <= 8; ++a) {
            const float* xa = x + (t + a) * XP + dq * 32;
            float acc = 0.f;
            #pragma unroll
            for (int i = 0; i < 8; ++i) {
                float4 va = *(const float4*)(xa + i * 4);
                acc += v0[i].x * va.x + v0[i].y * va.y + v0[i].z * va.z + v0[i].w * va.w;
            }
            part[dq * 264 + (a - 1) * 32 + t] = acc;
        }
    }
    __syncthreads();

    {   // reduce over dq, scale, mask
        int tt = tid & 31, a0 = tid >> 5;   // a = a0+1
        int a = a0 + 1;
        float dsum = 0.f;
        #pragma unroll
        for (int dq = 0; dq < 8; ++dq) dsum += part[dq * 264 + a0 * 32 + tt];
        float s = (dsum * scl[tt] * scl[tt + a] + 1.f) * 0.5f * msk[tt] * msk[tt + a];
        sb[a * 33 + tt] = s;
    }
    if (tid < 32) {
        float r0 = nrm[tid] / (nrm[tid] + EPSN);
        sb[tid] = (r0 * r0 - DS_ + 1.f) * 0.5f * msk[tid] * msk[tid];
    }
    __syncthreads();

    if (tid < 64) {   // pack 16 bf16 band-slots per t, coalesced 16B stores
        int tt = tid & 31, h = tid >> 5;
        ushort8_t o;
        #pragma unroll
        for (int e = 0; e < 8; ++e) {
            int a = h * 8 + e;
            o[e] = (a <= 8) ? f2bf(sb[a * 33 + tt]) : (unsigned short)0;
        }
        *(ushort8_t*)(s16g + ((size_t)(mod * B_ + b) * T_ + t0 + tt) * 16 + h * 8) = o;
    }
}

// ===================== Kernel B: MFMA conv stack + masked GAP partials =====================
#define TT 128
#define G_ 16
#define WB 160            // TT + 2*G_
#define HP 68             // h-buffer pitch (bf16 elems); 136B rows -> dword-conflict-free
#define WLP 196           // dconv weight pitch
#define WPP 68            // pw weight pitch
// LDS map (bytes): [0,33792) weights-union | bufA 21760 | bufB 21760 | mld 512 | red 1024 | slack
#define OFF_BUFA 33792
#define OFF_BUFB (33792 + 21760)
#define OFF_MLD  (33792 + 43520)
#define OFF_RED  (OFF_MLD + 512)
#define SMEM_CONV (OFF_RED + 1024 + 1024)

static __device__ __forceinline__ f32x4 mfma_bf16(bfrag a, bfrag b, f32x4 c) {
    return __builtin_amdgcn_mfma_f32_16x16x32_bf16(a, b, c, 0, 0, 0);
}

template<int DIL>
static __device__ __forceinline__ void conv_stage(
    unsigned short* __restrict__ wlds, unsigned short* __restrict__ wp,
    unsigned short* __restrict__ bufIn, unsigned short* __restrict__ bufOut,
    const float* __restrict__ w_d, const float* __restrict__ b_d,
    const float* __restrict__ w_p, const float* __restrict__ b_p,
    int t0, int tid, int l15, int lg, int mt0, int wn)
{
    // stage weights: wlds[c][tap*64+ci] <- w_d[c][ci][tap]; wp[c][ci]
    for (int idx = tid; idx < 64 * 192; idx += 256) {
        int c = idx / 192, r = idx - c * 192;
        int ci = r / 3, tap = r - ci * 3;
        wlds[c * WLP + tap * 64 + ci] = f2bf(w_d[idx]);
    }
    for (int idx = tid; idx < 64 * 64; idx += 256) {
        int c = idx >> 6, ci = idx & 63;
        wp[c * WPP + ci] = f2bf(w_p[idx]);
    }
    __syncthreads();

    // ---- dilated 3-tap conv as K=192 GEMM (k = tap*64 + ci), bufIn -> bufOut
    {
        bfrag ad[2][6];
        float bd[2][4];
        #pragma unroll
        for (int m = 0; m < 2; ++m) {
            int row = (mt0 + m) * 16 + l15;
            #pragma unroll
            for (int ks = 0; ks < 6; ++ks) {
                int tap = ks >> 1, half = ks & 1;
                ad[m][ks] = *(const bfrag*)(wlds + row * WLP + tap * 64 + half * 32 + lg * 8);
            }
            #pragma unroll
            for (int r = 0; r < 4; ++r) bd[m][r] = b_d[(mt0 + m) * 16 + lg * 4 + r];
        }
        for (int nt = wn * 5; nt < wn * 5 + 5; ++nt) {
            int j = nt * 16 + l15;
            f32x4 acc0 = {0.f, 0.f, 0.f, 0.f}, acc1 = {0.f, 0.f, 0.f, 0.f};
            #pragma unroll
            for (int ks = 0; ks < 6; ++ks) {
                int tap = ks >> 1, half = ks & 1;
                int brow = j + (tap - 1) * DIL;
                bfrag bv = *(const bfrag*)(bufIn + brow * HP + half * 32 + lg * 8);
                acc0 = mfma_bf16(ad[0][ks], bv, acc0);
                acc1 = mfma_bf16(ad[1][ks], bv, acc1);
            }
            int tg = t0 - G_ + j;
            bool valid = (tg >= 0 && tg < T_);
            #pragma unroll
            for (int m = 0; m < 2; ++m) {
                f32x4 acc = m ? acc1 : acc0;
                ushort4_t pk;
                #pragma unroll
                for (int r = 0; r < 4; ++r) {
                    float v = acc[r] + bd[m][r];
                    v = valid ? fmaxf(v, 0.f) : 0.f;
                    pk[r] = f2bf(v);
                }
                *(ushort4_t*)(bufOut + j * HP + (mt0 + m) * 16 + lg * 4) = pk;
            }
        }
    }
    __syncthreads();

    // ---- pointwise conv as K=64 GEMM, bufOut -> bufIn
    {
        bfrag ap[2][2];
        float bpv[2][4];
        #pragma unroll
        for (int m = 0; m < 2; ++m) {
            int row = (mt0 + m) * 16 + l15;
            #pragma unroll
            for (int half = 0; half < 2; ++half)
                ap[m][half] = *(const bfrag*)(wp + row * WPP + half * 32 + lg * 8);
            #pragma unroll
            for (int r = 0; r < 4; ++r) bpv[m][r] = b_p[(mt0 + m) * 16 + lg * 4 + r];
        }
        for (int nt = wn * 5; nt < wn * 5 + 5; ++nt) {
            int j = nt * 16 + l15;
            f32x4 acc0 = {0.f, 0.f, 0.f, 0.f}, acc1 = {0.f, 0.f, 0.f, 0.f};
            #pragma unroll
            for (int half = 0; half < 2; ++half) {
                bfrag bv = *(const bfrag*)(bufOut + j * HP + half * 32 + lg * 8);
                acc0 = mfma_bf16(ap[0][half], bv, acc0);
                acc1 = mfma_bf16(ap[1][half], bv, acc1);
            }
            int tg = t0 - G_ + j;
            bool valid = (tg >= 0 && tg < T_);
            #pragma unroll
            for (int m = 0; m < 2; ++m) {
                f32x4 acc = m ? acc1 : acc0;
                ushort4_t pk;
                #pragma unroll
                for (int r = 0; r < 4; ++r) {
                    float v = acc[r] + bpv[m][r];
                    v = valid ? fmaxf(v, 0.f) : 0.f;
                    pk[r] = f2bf(v);
                }
                *(ushort4_t*)(bufIn + j * HP + (mt0 + m) * 16 + lg * 4) = pk;
            }
        }
    }
    __syncthreads();
}

__global__ __launch_bounds__(256, 2) void conv_mfma_kernel(
    const unsigned short* __restrict__ s16g,
    const float* __restrict__ mask0, const float* __restrict__ mask1,
    const float* __restrict__ w_in, const float* __restrict__ b_in,
    const float* __restrict__ w_d1, const float* __restrict__ b_d1,
    const float* __restrict__ w_p1, const float* __restrict__ b_p1,
    const float* __restrict__ w_d2, const float* __restrict__ b_d2,
    const float* __restrict__ w_p2, const float* __restrict__ b_p2,
    const float* __restrict__ w_d3, const float* __restrict__ b_d3,
    const float* __restrict__ w_p3, const float* __restrict__ b_p3,
    float* __restrict__ z_part)        // [2*B][32][64]
{
    extern __shared__ char sm[];
    unsigned short* wreg = (unsigned short*)sm;        // union region
    unsigned short* wlds = wreg;                       // [64][WLP]
    unsigned short* wp   = wreg + 64 * WLP;            // [64][WPP]
    unsigned short* sbuf = wreg;                       // [WB][16]   (in-conv phase only)
    unsigned short* weff = wreg + WB * 16;             // [64][16]
    unsigned short* bufA = (unsigned short*)(sm + OFF_BUFA);
    unsigned short* bufB = (unsigned short*)(sm + OFF_BUFB);
    float* mld = (float*)(sm + OFF_MLD);               // [TT]
    float* red = (float*)(sm + OFF_RED);               // [4][64]

    int bid  = blockIdx.x;                             // 2*B*32 = 2048
    int tile = bid & 31;
    int b    = (bid >> 5) & 31;
    int mod  = bid >> 10;
    int mb   = mod * B_ + b;
    const float* mask = mod ? mask1 : mask0;
    int t0  = tile * TT;
    int tid = threadIdx.x;
    int w = tid >> 6, lane = tid & 63;
    int l15 = lane & 15, lg = lane >> 4;
    int wm = w >> 1, wn = w & 1;
    int mt0 = wm * 2;

    // ---- stage s16 tile (with t-bounds zero fill), folded in-conv weights, mask
    {
        const unsigned short* srow = s16g + (size_t)mb * T_ * 16;
        for (int ch = tid; ch < WB * 2; ch += 256) {
            int j = ch >> 1, q = ch & 1;
            int t = t0 - G_ + j;
            ushort8_t v = {0, 0, 0, 0, 0, 0, 0, 0};
            if (t >= 0 && t < T_) v = *(const ushort8_t*)(srow + (size_t)t * 16 + q * 8);
            *(ushort8_t*)(sbuf + j * 16 + q * 8) = v;
        }
        if (tid < 64) {
            #pragma unroll
            for (int a = 0; a < 16; ++a) {
                float wv = 0.f;
                if (a <= 8) {
                    wv = w_in[tid * 17 + 8 + a];
                    if (a > 0) wv += w_in[tid * 17 + 8 - a];
                }
                weff[tid * 16 + a] = f2bf(wv);
            }
        }
        if (tid < TT) {
            int tg = t0 + tid;
            mld[tid] = (tg < T_) ? mask[(size_t)b * T_ + tg] : 0.f;
        }
    }
    __syncthreads();

    // ---- in-conv (K=9 padded into one masked K=32 MFMA step) -> bufA
    {
        int lg2 = lg & 1;
        bfrag a_in[2];
        float bi[2][4];
        #pragma unroll
        for (int m = 0; m < 2; ++m) {
            int row = (mt0 + m) * 16 + l15;
            a_in[m] = *(const bfrag*)(weff + row * 16 + lg2 * 8);
            #pragma unroll
            for (int r = 0; r < 4; ++r) bi[m][r] = b_in[(mt0 + m) * 16 + lg * 4 + r];
        }
        for (int nt = wn * 5; nt < wn * 5 + 5; ++nt) {
            int j = nt * 16 + l15;
            bfrag bv = {0, 0, 0, 0, 0, 0, 0, 0};
            if (lg < 2) bv = *(const bfrag*)(sbuf + j * 16 + lg * 8);
            f32x4 acc0 = {0.f, 0.f, 0.f, 0.f}, acc1 = {0.f, 0.f, 0.f, 0.f};
            acc0 = mfma_bf16(a_in[0], bv, acc0);
            acc1 = mfma_bf16(a_in[1], bv, acc1);
            int tg = t0 - G_ + j;
            bool valid = (tg >= 0 && tg < T_);
            #pragma unroll
            for (int m = 0; m < 2; ++m) {
                f32x4 acc = m ? acc1 : acc0;
                ushort4_t pk;
                #pragma unroll
                for (int r = 0; r < 4; ++r) {
                    float v = acc[r] + bi[m][r];
                    v = valid ? fmaxf(v, 0.f) : 0.f;
                    pk[r] = f2bf(v);
                }
                *(ushort4_t*)(bufA + j * HP + (mt0 + m) * 16 + lg * 4) = pk;
            }
        }
    }
    __syncthreads();

    conv_stage<1>(wlds, wp, bufA, bufB, w_d1, b_d1, w_p1, b_p1, t0, tid, l15, lg, mt0, wn);
    conv_stage<2>(wlds, wp, bufA, bufB, w_d2, b_d2, w_p2, b_p2, t0, tid, l15, lg, mt0, wn);
    conv_stage<4>(wlds, wp, bufA, bufB, w_d3, b_d3, w_p3, b_p3, t0, tid, l15, lg, mt0, wn);

    // ---- masked GAP partial over this tile's 128 cols (j in [G_, G_+TT))
    {
        int c = tid & 63, g = tid >> 6;
        float acc = 0.f;
        #pragma unroll 4
        for (int i = 0; i < 32; ++i) {
            int jj = g * 32 + i;
            acc += bf2f(bufA[(G_ + jj) * HP + c]) * mld[jj];
        }
        red[g * 64 + c] = acc;
    }
    __syncthreads();
    if (tid < 64) {
        float z = red[tid] + red[64 + tid] + red[128 + tid] + red[192 + tid];
        z_part[((size_t)mb * 32 + tile) * 64 + tid] = z;
    }
}

// ===================== Kernel C: GAP divide + LayerNorm + gates =====================
__global__ __launch_bounds__(128) void gates_kernel(
    const float* __restrict__ z_part,
    const float* __restrict__ mask0, const float* __restrict__ mask1,
    const float* __restrict__ ln_g, const float* __restrict__ ln_b,
    const float* __restrict__ mha_w1, const float* __restrict__ mha_b1,
    const float* __restrict__ mha_w2, const float* __restrict__ mha_b2,
    const float* __restrict__ ffn_w1, const float* __restrict__ ffn_b1,
    const float* __restrict__ ffn_w2, const float* __restrict__ ffn_b2,
    float* __restrict__ out)
{
    __shared__ float fn[128];
    __shared__ float red[4];
    __shared__ float msum[2];
    int b = blockIdx.x, tid = threadIdx.x;
    int mod = tid >> 6, c = tid & 63;

    float z = 0.f;
    for (int tl = 0; tl < 32; ++tl)
        z += z_part[((size_t)(mod * B_ + b) * 32 + tl) * 64 + c];

    const float* mk = mod ? mask1 : mask0;
    float ms = 0.f;
    for (int t = c; t < T_; t += 64) ms += mk[(size_t)b * T_ + t];
    #pragma unroll
    for (int o = 32; o > 0; o >>= 1) ms += __shfl_xor(ms, o);
    if (c == 0) msum[mod] = ms;
    __syncthreads();

    float fv = z / (msum[mod] + EPSG);
    float s1 = fv, s2 = fv * fv;
    #pragma unroll
    for (int o = 32; o > 0; o >>= 1) { s1 += __shfl_xor(s1, o); s2 += __shfl_xor(s2, o); }
    if (c == 0) { red[mod * 2] = s1; red[mod * 2 + 1] = s2; }
    __syncthreads();

    float mu  = (red[0] + red[2]) * (1.0f / 128.0f);
    float ex2 = (red[1] + red[3]) * (1.0f / 128.0f);
    float var = ex2 - mu * mu;
    float fnv = (fv - mu) * rsqrtf(var + EPSL) * ln_g[tid] + ln_b[tid];
    fn[tid] = fnv;
    __syncthreads();

    const float* W1 = mod ? ffn_w1 : mha_w1;
    const float* B1 = mod ? ffn_b1 : mha_b1;
    const float* W2 = mod ? ffn_w2 : mha_w2;
    const float* B2 = mod ? ffn_b2 : mha_b2;
    float r = B1[c];
    for (int i = 0; i < 128; ++i) r += fn[i] * W1[i * 64 + c];
    r = fmaxf(r, 0.f);
    float g = r * W2[c];
    #pragma unroll
    for (int o = 32; o > 0; o >>= 1) g += __shfl_xor(g, o);
    if (c == 0) {
        g += B2[0];
        out[mod * B_ + b] = mod ? tanhf(g) : 1.0f / (1.0f + expf(-g));
    }
}

// ===================== launch =====================
extern "C" void kernel_launch(void* const* d_in, const int* in_sizes, int n_in,
                              void* d_out, int out_size, void* d_ws, size_t ws_size,
                              hipStream_t stream) {
    const float* video_feat = (const float*)d_in[0];
    const float* audio_feat = (const float*)d_in[1];
    const float* video_mask = (const float*)d_in[2];
    const float* audio_mask = (const float*)d_in[3];
    const float* w_in = (const float*)d_in[4];
    const float* b_in = (const float*)d_in[5];
    const float* w_d1 = (const float*)d_in[6];
    const float* b_d1 = (const float*)d_in[7];
    const float* w_p1 = (const float*)d_in[8];
    const float* b_p1 = (const float*)d_in[9];
    const float* w_d2 = (const float*)d_in[10];
    const float* b_d2 = (const float*)d_in[11];
    const float* w_p2 = (const float*)d_in[12];
    const float* b_p2 = (const float*)d_in[13];
    const float* w_d3 = (const float*)d_in[14];
    const float* b_d3 = (const float*)d_in[15];
    const float* w_p3 = (const float*)d_in[16];
    const float* b_p3 = (const float*)d_in[17];
    const float* ln_g = (const float*)d_in[18];
    const float* ln_b = (const float*)d_in[19];
    const float* mha_w1 = (const float*)d_in[20];
    const float* mha_b1 = (const float*)d_in[21];
    const float* mha_w2 = (const float*)d_in[22];
    const float* mha_b2 = (const float*)d_in[23];
    const float* ffn_w1 = (const float*)d_in[24];
    const float* ffn_b1 = (const float*)d_in[25];
    const float* ffn_w2 = (const float*)d_in[26];
    const float* ffn_b2 = (const float*)d_in[27];

    unsigned short* s16g = (unsigned short*)d_ws;                       // 2*B*T*16 bf16 = 8.39 MB
    float* z_part = (float*)((char*)d_ws + (size_t)2 * B_ * T_ * 16 * 2);  // 2*B*32*64 f32

    strip_kernel<<<dim3(2 * B_ * (T_ / TS)), dim3(256), 0, stream>>>(
        audio_feat, audio_mask, video_feat, video_mask, s16g);

    hipFuncSetAttribute((const void*)conv_mfma_kernel,
                        hipFuncAttributeMaxDynamicSharedMemorySize, SMEM_CONV);
    conv_mfma_kernel<<<dim3(2 * B_ * (T_ / TT)), dim3(256), SMEM_CONV, stream>>>(
        s16g, audio_mask, video_mask,
        w_in, b_in, w_d1, b_d1, w_p1, b_p1, w_d2, b_d2, w_p2, b_p2,
        w_d3, b_d3, w_p3, b_p3, z_part);

    gates_kernel<<<dim3(B_), dim3(128), 0, stream>>>(
        z_part, audio_mask, video_mask, ln_g, ln_b,
        mha_w1, mha_b1, mha_w2, mha_b2, ffn_w1, ffn_b1, ffn_w2, ffn_b2,
        (float*)d_out);
}

// Round 3
// 191.721 us; speedup vs baseline: 8.3444x; 1.6335x over previous
//
#include <hip/hip_runtime.h>
#include <math.h>

#define B_ 32
#define T_ 4096
#define D_ 256
#define C_ 64
#define EPSN 1e-6f
#define EPSG 1e-6f
#define EPSL 1e-5f
#define DS_ 0.1f

typedef short bfrag __attribute__((ext_vector_type(8)));      // 8 bf16 = 4 VGPR
typedef float f32x4 __attribute__((ext_vector_type(4)));
typedef unsigned short ushort4_t __attribute__((ext_vector_type(4)));
typedef unsigned short ushort8_t __attribute__((ext_vector_type(8)));

static __device__ __forceinline__ unsigned short f2bf(float f) {
    unsigned int u = __builtin_bit_cast(unsigned int, f);
    unsigned int r = u + 0x7fffu + ((u >> 16) & 1u);
    return (unsigned short)(r >> 16);
}
static __device__ __forceinline__ float bf2f(unsigned short u) {
    return __builtin_bit_cast(float, ((unsigned int)u) << 16);
}

// ===================== Kernel P: prepack weights -> bf16 fragment-layout images =====================
// wk layout (ushort): [0,1024) weff[64][16] folded w_in; then per stage s: at 1024+s*16384:
//   [0,12288) wd_img[c][tap*64+ci], [12288,16384) wp_img[c][ci]
__global__ __launch_bounds__(256) void prepack_kernel(
    const float* __restrict__ w_in,
    const float* __restrict__ wd0, const float* __restrict__ wp0,
    const float* __restrict__ wd1, const float* __restrict__ wp1,
    const float* __restrict__ wd2, const float* __restrict__ wp2,
    unsigned short* __restrict__ wk)
{
    int idx = blockIdx.x * 256 + threadIdx.x;
    if (idx >= 1024 + 3 * 16384) return;
    if (idx < 1024) {
        int c = idx >> 4, a = idx & 15;
        float wv = 0.f;
        if (a <= 8) {
            wv = w_in[c * 17 + 8 + a];
            if (a > 0) wv += w_in[c * 17 + 8 - a];
        }
        wk[idx] = f2bf(wv);
    } else {
        int i2 = idx - 1024;
        int s = i2 >> 14;
        int r = i2 & 16383;
        const float* wd = s == 0 ? wd0 : (s == 1 ? wd1 : wd2);
        const float* wp = s == 0 ? wp0 : (s == 1 ? wp1 : wp2);
        unsigned short v;
        if (r < 12288) {
            int c = r / 192, k = r - c * 192;
            int tap = k >> 6, ci = k & 63;
            v = f2bf(wd[c * 192 + ci * 3 + tap]);
        } else {
            v = f2bf(wp[r - 12288]);
        }
        wk[idx] = v;
    }
}

// ===================== Kernel A: normalize + banded strip -> s16 (bf16 [mb][t][16]) =====================
#define TS 32
#define RROWS 40
#define XP 260          // f32 pitch: 16B-aligned rows, dword-bank conflict-free for float4 reads

__global__ __launch_bounds__(256, 3) void strip_kernel(
    const float* __restrict__ feat0, const float* __restrict__ mask0,
    const float* __restrict__ feat1, const float* __restrict__ mask1,
    unsigned short* __restrict__ s16g)     // [2*B][T][16] bf16, slots 0..8 = bands, 9..15 = 0
{
    __shared__ float x[RROWS * XP];
    __shared__ float part[8 * 264];
    __shared__ float sb[9 * 33];
    __shared__ float nrm[RROWS], scl[RROWS], msk[RROWS];

    int bid  = blockIdx.x;
    int tile = bid & 127;            // T_/TS = 128
    int b    = (bid >> 7) & 31;
    int mod  = bid >> 12;
    const float* feat = mod ? feat1 : feat0;
    const float* mask = mod ? mask1 : mask0;
    int t0 = tile * TS;
    int tid = threadIdx.x;
    int w = tid >> 6, lane = tid & 63;

    for (int r = w; r < RROWS; r += 4) {
        int tg = t0 + r;
        float4 v = make_float4(0.f, 0.f, 0.f, 0.f);
        if (tg < T_) v = *(const float4*)(feat + ((size_t)b * T_ + tg) * D_ + lane * 4);
        *(float4*)(x + r * XP + lane * 4) = v;
    }
    if (tid < RROWS) {
        int tg = t0 + tid;
        msk[tid] = (tg < T_) ? mask[(size_t)b * T_ + tg] : 0.f;
    }
    __syncthreads();

    if (tid < 160) {
        int r = tid >> 2, q = tid & 3;
        const float* xr = x + r * XP + q * 64;
        float ss = 0.f;
        #pragma unroll
        for (int i = 0; i < 16; ++i) {
            float4 v = *(const float4*)(xr + i * 4);
            ss += v.x * v.x + v.y * v.y + v.z * v.z + v.w * v.w;
        }
        ss += __shfl_xor(ss, 1);
        ss += __shfl_xor(ss, 2);
        if (q == 0) {
            float n = sqrtf(ss);
            float m = msk[r];
            float nm = m * n;
            nrm[r] = nm;
            scl[r] = m / (nm + EPSN);
        }
    }
    __syncthreads();

    {   // banded raw dots, d-chunked: thread = (t, dq)
        int t = tid & 31, dq = tid >> 5;
        float4 v0[8];
        const float* xrow = x + t * XP + dq * 32;
        #pragma unroll
        for (int i = 0; i < 8; ++i) v0[i] = *(const float4*)(xrow + i * 4);
        #pragma unroll
        for (int a = 1; a <= 8; ++a) {
            const float* xa = x + (t + a) * XP + dq * 32;
            float acc = 0.f;
            #pragma unroll
            for (int i = 0; i < 8; ++i) {
                float4 va = *(const float4*)(xa + i * 4);
                acc += v0[i].x * va.x + v0[i].y * va.y + v0[i].z * va.z + v0[i].w * va.w;
            }
            part[dq * 264 + (a - 1) * 32 + t] = acc;
        }
    }
    __syncthreads();

    {   // reduce over dq, scale, mask
        int tt = tid & 31, a0 = tid >> 5;
        int a = a0 + 1;
        float dsum = 0.f;
        #pragma unroll
        for (int dq = 0; dq < 8; ++dq) dsum += part[dq * 264 + a0 * 32 + tt];
        float s = (dsum * scl[tt] * scl[tt + a] + 1.f) * 0.5f * msk[tt] * msk[tt + a];
        sb[a * 33 + tt] = s;
    }
    if (tid < 32) {
        float r0 = nrm[tid] / (nrm[tid] + EPSN);
        sb[tid] = (r0 * r0 - DS_ + 1.f) * 0.5f * msk[tid] * msk[tid];
    }
    __syncthreads();

    if (tid < 64) {   // pack 16 bf16 band-slots per t, coalesced 16B stores
        int tt = tid & 31, h = tid >> 5;
        ushort8_t o;
        #pragma unroll
        for (int e = 0; e < 8; ++e) {
            int a = h * 8 + e;
            o[e] = (a <= 8) ? f2bf(sb[a * 33 + tt]) : (unsigned short)0;
        }
        *(ushort8_t*)(s16g + ((size_t)(mod * B_ + b) * T_ + t0 + tt) * 16 + h * 8) = o;
    }
}

// ===================== Kernel B: MFMA conv stack + masked GAP partials =====================
#define TT 128
#define G_ 16
#define WB 160            // TT + 2*G_
#define SBP 24            // sbuf pitch (48B rows: 16B-aligned, conflict-free)
// h-buffers: [row][64ch] bf16, 128B rows, 16B-slot XOR swizzle (slot ^= row&7)
// LDS map (bytes): sbuf [0,7680) | guard 512 | bufA 8192..28672 | bufB 28672..49152 | mld 49664 | red 50176
#define OFF_BUFA 8192
#define OFF_BUFB 28672
#define OFF_MLD  49664
#define OFF_RED  50176
#define SMEM_TOT (OFF_RED + 1024)

static __device__ __forceinline__ f32x4 mfma_bf16(bfrag a, bfrag b, f32x4 c) {
    return __builtin_amdgcn_mfma_f32_16x16x32_bf16(a, b, c, 0, 0, 0);
}
// swizzled ushort index: 16B slot su (0..7) of row, XOR'd by row&7; off = ushort offset in slot
static __device__ __forceinline__ int swzi(int row, int su, int off) {
    return row * 64 + ((su ^ (row & 7)) << 3) + off;
}

template<int DIL>
static __device__ __forceinline__ void conv_stage(
    const unsigned short* __restrict__ wdg, const unsigned short* __restrict__ wpg,
    unsigned short* __restrict__ bufIn, unsigned short* __restrict__ bufOut,
    const float* __restrict__ b_d, const float* __restrict__ b_p,
    int t0, int l15, int lg, int mt0, int wn)
{
    // ---- dilated 3-tap conv as K=192 GEMM (k = tap*64 + ci), bufIn -> bufOut
    {
        bfrag ad[2][6];
        float bd[2][4];
        #pragma unroll
        for (int m = 0; m < 2; ++m) {
            int row = (mt0 + m) * 16 + l15;
            #pragma unroll
            for (int ks = 0; ks < 6; ++ks) {
                int tap = ks >> 1, half = ks & 1;
                ad[m][ks] = *(const bfrag*)(wdg + row * 192 + tap * 64 + half * 32 + lg * 8);
            }
            #pragma unroll
            for (int r = 0; r < 4; ++r) bd[m][r] = b_d[(mt0 + m) * 16 + lg * 4 + r];
        }
        for (int nt = wn * 5; nt < wn * 5 + 5; ++nt) {
            int j = nt * 16 + l15;
            f32x4 acc0 = {0.f, 0.f, 0.f, 0.f}, acc1 = {0.f, 0.f, 0.f, 0.f};
            #pragma unroll
            for (int ks = 0; ks < 6; ++ks) {
                int tap = ks >> 1, half = ks & 1;
                int brow = j + (tap - 1) * DIL;
                bfrag bv = *(const bfrag*)(bufIn + swzi(brow, half * 4 + lg, 0));
                acc0 = mfma_bf16(ad[0][ks], bv, acc0);
                acc1 = mfma_bf16(ad[1][ks], bv, acc1);
            }
            int tg = t0 - G_ + j;
            bool valid = (tg >= 0 && tg < T_);
            #pragma unroll
            for (int m = 0; m < 2; ++m) {
                f32x4 acc = m ? acc1 : acc0;
                ushort4_t pk;
                #pragma unroll
                for (int r = 0; r < 4; ++r) {
                    float v = acc[r] + bd[m][r];
                    v = valid ? fmaxf(v, 0.f) : 0.f;
                    pk[r] = f2bf(v);
                }
                *(ushort4_t*)(bufOut + swzi(j, (mt0 + m) * 2 + (lg >> 1), (lg & 1) * 4)) = pk;
            }
        }
    }
    __syncthreads();

    // ---- pointwise conv as K=64 GEMM, bufOut -> bufIn
    {
        bfrag ap[2][2];
        float bpv[2][4];
        #pragma unroll
        for (int m = 0; m < 2; ++m) {
            int row = (mt0 + m) * 16 + l15;
            #pragma unroll
            for (int half = 0; half < 2; ++half)
                ap[m][half] = *(const bfrag*)(wpg + row * 64 + half * 32 + lg * 8);
            #pragma unroll
            for (int r = 0; r < 4; ++r) bpv[m][r] = b_p[(mt0 + m) * 16 + lg * 4 + r];
        }
        for (int nt = wn * 5; nt < wn * 5 + 5; ++nt) {
            int j = nt * 16 + l15;
            f32x4 acc0 = {0.f, 0.f, 0.f, 0.f}, acc1 = {0.f, 0.f, 0.f, 0.f};
            #pragma unroll
            for (int half = 0; half < 2; ++half) {
                bfrag bv = *(const bfrag*)(bufOut + swzi(j, half * 4 + lg, 0));
                acc0 = mfma_bf16(ap[0][half], bv, acc0);
                acc1 = mfma_bf16(ap[1][half], bv, acc1);
            }
            int tg = t0 - G_ + j;
            bool valid = (tg >= 0 && tg < T_);
            #pragma unroll
            for (int m = 0; m < 2; ++m) {
                f32x4 acc = m ? acc1 : acc0;
                ushort4_t pk;
                #pragma unroll
                for (int r = 0; r < 4; ++r) {
                    float v = acc[r] + bpv[m][r];
                    v = valid ? fmaxf(v, 0.f) : 0.f;
                    pk[r] = f2bf(v);
                }
                *(ushort4_t*)(bufIn + swzi(j, (mt0 + m) * 2 + (lg >> 1), (lg & 1) * 4)) = pk;
            }
        }
    }
    __syncthreads();
}

__global__ __launch_bounds__(256, 3) void conv_mfma_kernel(
    const unsigned short* __restrict__ s16g,
    const float* __restrict__ mask0, const float* __restrict__ mask1,
    const unsigned short* __restrict__ wk,
    const float* __restrict__ b_in,
    const float* __restrict__ b_d1, const float* __restrict__ b_p1,
    const float* __restrict__ b_d2, const float* __restrict__ b_p2,
    const float* __restrict__ b_d3, const float* __restrict__ b_p3,
    float* __restrict__ z_part)        // [2*B][32][64]
{
    __shared__ __align__(16) char smem[SMEM_TOT];
    unsigned short* sbuf = (unsigned short*)smem;                 // [WB][SBP]
    unsigned short* bufA = (unsigned short*)(smem + OFF_BUFA);
    unsigned short* bufB = (unsigned short*)(smem + OFF_BUFB);
    float* mld = (float*)(smem + OFF_MLD);                        // [TT]
    float* red = (float*)(smem + OFF_RED);                        // [4][64]

    int bid  = blockIdx.x;                             // 2*B*32 = 2048
    int tile = bid & 31;
    int b    = (bid >> 5) & 31;
    int mod  = bid >> 10;
    int mb   = mod * B_ + b;
    const float* mask = mod ? mask1 : mask0;
    int t0  = tile * TT;
    int tid = threadIdx.x;
    int lane = tid & 63;
    int w = tid >> 6;
    int l15 = lane & 15, lg = lane >> 4;
    int wm = w >> 1, wn = w & 1;
    int mt0 = wm * 2;

    const unsigned short* weff_g = wk;

    // ---- stage s16 tile (with t-bounds zero fill) + mask
    {
        const unsigned short* srow = s16g + (size_t)mb * T_ * 16;
        for (int ch = tid; ch < WB * 2; ch += 256) {
            int j = ch >> 1, q = ch & 1;
            int t = t0 - G_ + j;
            ushort8_t v = {0, 0, 0, 0, 0, 0, 0, 0};
            if (t >= 0 && t < T_) v = *(const ushort8_t*)(srow + (size_t)t * 16 + q * 8);
            *(ushort8_t*)(sbuf + j * SBP + q * 8) = v;
        }
        if (tid < TT) {
            int tg = t0 + tid;
            mld[tid] = (tg < T_) ? mask[(size_t)b * T_ + tg] : 0.f;
        }
    }
    __syncthreads();

    // ---- in-conv (K=9 padded into one masked K=32 MFMA step) -> bufA
    {
        int lg2 = lg & 1;
        bfrag a_in[2];
        float bi[2][4];
        #pragma unroll
        for (int m = 0; m < 2; ++m) {
            int row = (mt0 + m) * 16 + l15;
            a_in[m] = *(const bfrag*)(weff_g + row * 16 + lg2 * 8);
            #pragma unroll
            for (int r = 0; r < 4; ++r) bi[m][r] = b_in[(mt0 + m) * 16 + lg * 4 + r];
        }
        for (int nt = wn * 5; nt < wn * 5 + 5; ++nt) {
            int j = nt * 16 + l15;
            bfrag bv = {0, 0, 0, 0, 0, 0, 0, 0};
            if (lg < 2) bv = *(const bfrag*)(sbuf + j * SBP + lg * 8);
            f32x4 acc0 = {0.f, 0.f, 0.f, 0.f}, acc1 = {0.f, 0.f, 0.f, 0.f};
            acc0 = mfma_bf16(a_in[0], bv, acc0);
            acc1 = mfma_bf16(a_in[1], bv, acc1);
            int tg = t0 - G_ + j;
            bool valid = (tg >= 0 && tg < T_);
            #pragma unroll
            for (int m = 0; m < 2; ++m) {
                f32x4 acc = m ? acc1 : acc0;
                ushort4_t pk;
                #pragma unroll
                for (int r = 0; r < 4; ++r) {
                    float v = acc[r] + bi[m][r];
                    v = valid ? fmaxf(v, 0.f) : 0.f;
                    pk[r] = f2bf(v);
                }
                *(ushort4_t*)(bufA + swzi(j, (mt0 + m) * 2 + (lg >> 1), (lg & 1) * 4)) = pk;
            }
        }
    }
    __syncthreads();

    conv_stage<1>(wk + 1024,             wk + 1024 + 12288,             bufA, bufB, b_d1, b_p1, t0, l15, lg, mt0, wn);
    conv_stage<2>(wk + 1024 + 16384,     wk + 1024 + 16384 + 12288,     bufA, bufB, b_d2, b_p2, t0, l15, lg, mt0, wn);
    conv_stage<4>(wk + 1024 + 2 * 16384, wk + 1024 + 2 * 16384 + 12288, bufA, bufB, b_d3, b_p3, t0, l15, lg, mt0, wn);

    // ---- masked GAP partial over this tile's 128 cols (j in [G_, G_+TT))
    {
        int c = tid & 63, g = tid >> 6;
        float acc = 0.f;
        #pragma unroll 4
        for (int i = 0; i < 32; ++i) {
            int jj = g * 32 + i;
            int r = G_ + jj;
            acc += bf2f(bufA[swzi(r, c >> 3, c & 7)]) * mld[jj];
        }
        red[g * 64 + c] = acc;
    }
    __syncthreads();
    if (tid < 64) {
        float z = red[tid] + red[64 + tid] + red[128 + tid] + red[192 + tid];
        z_part[((size_t)mb * 32 + tile) * 64 + tid] = z;
    }
}

// ===================== Kernel C: GAP divide + LayerNorm + gates =====================
__global__ __launch_bounds__(128) void gates_kernel(
    const float* __restrict__ z_part,
    const float* __restrict__ mask0, const float* __restrict__ mask1,
    const float* __restrict__ ln_g, const float* __restrict__ ln_b,
    const float* __restrict__ mha_w1, const float* __restrict__ mha_b1,
    const float* __restrict__ mha_w2, const float* __restrict__ mha_b2,
    const float* __restrict__ ffn_w1, const float* __restrict__ ffn_b1,
    const float* __restrict__ ffn_w2, const float* __restrict__ ffn_b2,
    float* __restrict__ out)
{
    __shared__ float fn[128];
    __shared__ float red[4];
    __shared__ float msum[2];
    int b = blockIdx.x, tid = threadIdx.x;
    int mod = tid >> 6, c = tid & 63;

    float z = 0.f;
    for (int tl = 0; tl < 32; ++tl)
        z += z_part[((size_t)(mod * B_ + b) * 32 + tl) * 64 + c];

    const float* mk = mod ? mask1 : mask0;
    float ms = 0.f;
    for (int t = c; t < T_; t += 64) ms += mk[(size_t)b * T_ + t];
    #pragma unroll
    for (int o = 32; o > 0; o >>= 1) ms += __shfl_xor(ms, o);
    if (c == 0) msum[mod] = ms;
    __syncthreads();

    float fv = z / (msum[mod] + EPSG);
    float s1 = fv, s2 = fv * fv;
    #pragma unroll
    for (int o = 32; o > 0; o >>= 1) { s1 += __shfl_xor(s1, o); s2 += __shfl_xor(s2, o); }
    if (c == 0) { red[mod * 2] = s1; red[mod * 2 + 1] = s2; }
    __syncthreads();

    float mu  = (red[0] + red[2]) * (1.0f / 128.0f);
    float ex2 = (red[1] + red[3]) * (1.0f / 128.0f);
    float var = ex2 - mu * mu;
    float fnv = (fv - mu) * rsqrtf(var + EPSL) * ln_g[tid] + ln_b[tid];
    fn[tid] = fnv;
    __syncthreads();

    const float* W1 = mod ? ffn_w1 : mha_w1;
    const float* B1 = mod ? ffn_b1 : mha_b1;
    const float* W2 = mod ? ffn_w2 : mha_w2;
    const float* B2 = mod ? ffn_b2 : mha_b2;
    float r = B1[c];
    for (int i = 0; i < 128; ++i) r += fn[i] * W1[i * 64 + c];
    r = fmaxf(r, 0.f);
    float g = r * W2[c];
    #pragma unroll
    for (int o = 32; o > 0; o >>= 1) g += __shfl_xor(g, o);
    if (c == 0) {
        g += B2[0];
        out[mod * B_ + b] = mod ? tanhf(g) : 1.0f / (1.0f + expf(-g));
    }
}

// ===================== launch =====================
extern "C" void kernel_launch(void* const* d_in, const int* in_sizes, int n_in,
                              void* d_out, int out_size, void* d_ws, size_t ws_size,
                              hipStream_t stream) {
    const float* video_feat = (const float*)d_in[0];
    const float* audio_feat = (const float*)d_in[1];
    const float* video_mask = (const float*)d_in[2];
    const float* audio_mask = (const float*)d_in[3];
    const float* w_in = (const float*)d_in[4];
    const float* b_in = (const float*)d_in[5];
    const float* w_d1 = (const float*)d_in[6];
    const float* b_d1 = (const float*)d_in[7];
    const float* w_p1 = (const float*)d_in[8];
    const float* b_p1 = (const float*)d_in[9];
    const float* w_d2 = (const float*)d_in[10];
    const float* b_d2 = (const float*)d_in[11];
    const float* w_p2 = (const float*)d_in[12];
    const float* b_p2 = (const float*)d_in[13];
    const float* w_d3 = (const float*)d_in[14];
    const float* b_d3 = (const float*)d_in[15];
    const float* w_p3 = (const float*)d_in[16];
    const float* b_p3 = (const float*)d_in[17];
    const float* ln_g = (const float*)d_in[18];
    const float* ln_b = (const float*)d_in[19];
    const float* mha_w1 = (const float*)d_in[20];
    const float* mha_b1 = (const float*)d_in[21];
    const float* mha_w2 = (const float*)d_in[22];
    const float* mha_b2 = (const float*)d_in[23];
    const float* ffn_w1 = (const float*)d_in[24];
    const float* ffn_b1 = (const float*)d_in[25];
    const float* ffn_w2 = (const float*)d_in[26];
    const float* ffn_b2 = (const float*)d_in[27];

    unsigned short* s16g = (unsigned short*)d_ws;                          // 2*B*T*16 bf16 = 8.39 MB
    float* z_part = (float*)((char*)d_ws + (size_t)2 * B_ * T_ * 16 * 2);  // 2*B*32*64 f32 = 512 KB
    unsigned short* wk = (unsigned short*)((char*)z_part + (size_t)2 * B_ * 32 * 64 * 4);  // 100 KB

    prepack_kernel<<<dim3(196), dim3(256), 0, stream>>>(
        w_in, w_d1, w_p1, w_d2, w_p2, w_d3, w_p3, wk);

    strip_kernel<<<dim3(2 * B_ * (T_ / TS)), dim3(256), 0, stream>>>(
        audio_feat, audio_mask, video_feat, video_mask, s16g);

    conv_mfma_kernel<<<dim3(2 * B_ * (T_ / TT)), dim3(256), 0, stream>>>(
        s16g, audio_mask, video_mask, wk, b_in,
        b_d1, b_p1, b_d2, b_p2, b_d3, b_p3, z_part);

    gates_kernel<<<dim3(B_), dim3(128), 0, stream>>>(
        z_part, audio_mask, video_mask, ln_g, ln_b,
        mha_w1, mha_b1, mha_w2, mha_b2, ffn_w1, ffn_b1, ffn_w2, ffn_b2,
        (float*)d_out);
}

// Round 4
// 175.749 us; speedup vs baseline: 9.1027x; 1.0909x over previous
//
#include <hip/hip_runtime.h>
#include <math.h>

#define B_ 32
#define T_ 4096
#define D_ 256
#define C_ 64
#define EPSN 1e-6f
#define EPSG 1e-6f
#define EPSL 1e-5f
#define DS_ 0.1f

typedef short bfrag __attribute__((ext_vector_type(8)));      // 8 bf16 = 4 VGPR
typedef float f32x4 __attribute__((ext_vector_type(4)));
typedef unsigned short ushort4_t __attribute__((ext_vector_type(4)));
typedef unsigned short ushort8_t __attribute__((ext_vector_type(8)));

static __device__ __forceinline__ unsigned short f2bf(float f) {
    unsigned int u = __builtin_bit_cast(unsigned int, f);
    unsigned int r = u + 0x7fffu + ((u >> 16) & 1u);
    return (unsigned short)(r >> 16);
}
static __device__ __forceinline__ float bf2f(unsigned short u) {
    return __builtin_bit_cast(float, ((unsigned int)u) << 16);
}

static __device__ __forceinline__ f32x4 mfma_bf16(bfrag a, bfrag b, f32x4 c) {
    return __builtin_amdgcn_mfma_f32_16x16x32_bf16(a, b, c, 0, 0, 0);
}

// ===================== Kernel P: prepack weights -> bf16 fragment-layout images =====================
__global__ __launch_bounds__(256) void prepack_kernel(
    const float* __restrict__ w_in,
    const float* __restrict__ wd0, const float* __restrict__ wp0,
    const float* __restrict__ wd1, const float* __restrict__ wp1,
    const float* __restrict__ wd2, const float* __restrict__ wp2,
    unsigned short* __restrict__ wk)
{
    int idx = blockIdx.x * 256 + threadIdx.x;
    if (idx >= 1024 + 3 * 16384) return;
    if (idx < 1024) {
        int c = idx >> 4, a = idx & 15;
        float wv = 0.f;
        if (a <= 8) {
            wv = w_in[c * 17 + 8 + a];
            if (a > 0) wv += w_in[c * 17 + 8 - a];
        }
        wk[idx] = f2bf(wv);
    } else {
        int i2 = idx - 1024;
        int s = i2 >> 14;
        int r = i2 & 16383;
        const float* wd = s == 0 ? wd0 : (s == 1 ? wd1 : wd2);
        const float* wp = s == 0 ? wp0 : (s == 1 ? wp1 : wp2);
        unsigned short v;
        if (r < 12288) {
            int c = r / 192, k = r - c * 192;
            int tap = k >> 6, ci = k & 63;
            v = f2bf(wd[c * 192 + ci * 3 + tap]);
        } else {
            v = f2bf(wp[r - 12288]);
        }
        wk[idx] = v;
    }
}

// ===================== Kernel A: MFMA Gram-band strip -> s16 (bf16 [mb][t][16]) =====================
// Block: 256 thr (4 waves), RB=64 output rows, 16 halo rows. X staged bf16 in LDS,
// 16B-slot XOR swizzle (slot ^= row&7). Each wave: Gram tiles (r0,r0) and (r0,r0+16), K=256.
#define RB 64
#define XR 80

__global__ __launch_bounds__(256, 3) void strip_kernel(
    const float* __restrict__ feat0, const float* __restrict__ mask0,
    const float* __restrict__ feat1, const float* __restrict__ mask1,
    unsigned short* __restrict__ s16g)     // [2*B][T][16] bf16, slots 0..8 = bands, 9..15 = 0
{
    __shared__ unsigned short x[XR * 256];       // swizzled bf16 rows, 512 B/row
    __shared__ float dotbuf[4 * 16 * 32];        // per-wave 16x32 raw dots
    __shared__ float scl[XR];
    __shared__ float msk[XR];
    __shared__ float sdh[8];                     // halo self-dots rows 64..71

    int bid  = blockIdx.x;            // 2*B*64 = 4096
    int tile = bid & 63;
    int b    = (bid >> 6) & 31;
    int mod  = bid >> 11;
    int mb   = mod * B_ + b;
    const float* feat = mod ? feat1 : feat0;
    const float* mask = mod ? mask1 : mask0;
    int t0 = tile * RB;
    int tid = threadIdx.x;
    int w = tid >> 6, lane = tid & 63;
    int l15 = lane & 15, lg = lane >> 4;

    // ---- load 80 rows of X (f32 global, coalesced 1 KB/row) -> bf16 swizzled LDS
    {
        int su = lane >> 1, half = lane & 1;
        for (int i = 0; i < 20; ++i) {
            int r = w * 20 + i;
            int tg = t0 + r;
            float4 v = make_float4(0.f, 0.f, 0.f, 0.f);
            if (tg < T_) v = *(const float4*)(feat + ((size_t)b * T_ + tg) * D_ + lane * 4);
            ushort4_t u;
            u[0] = f2bf(v.x); u[1] = f2bf(v.y); u[2] = f2bf(v.z); u[3] = f2bf(v.w);
            *(ushort4_t*)(x + r * 256 + ((su ^ (r & 7)) << 3) + half * 4) = u;
        }
        if (tid < XR) {
            int tg = t0 + tid;
            msk[tid] = (tg < T_) ? mask[(size_t)b * T_ + tg] : 0.f;
        }
    }
    __syncthreads();

    // ---- Gram band via MFMA: tiles (r0,r0) and (r0,r0+16), K=256
    {
        int r0 = w * 16;
        int rowA = r0 + l15;
        int rowB = rowA + 16;
        f32x4 acc0 = {0.f, 0.f, 0.f, 0.f}, acc1 = {0.f, 0.f, 0.f, 0.f};
        #pragma unroll
        for (int ks = 0; ks < 8; ++ks) {
            int su = ks * 4 + lg;
            bfrag av = *(const bfrag*)(x + rowA * 256 + ((su ^ (rowA & 7)) << 3));
            bfrag bv = *(const bfrag*)(x + rowB * 256 + ((su ^ (rowB & 7)) << 3));
            acc0 = mfma_bf16(av, av, acc0);
            acc1 = mfma_bf16(av, bv, acc1);
        }
        #pragma unroll
        for (int r = 0; r < 4; ++r) {
            dotbuf[w * 512 + (lg * 4 + r) * 32 + l15] = acc0[r];
            dotbuf[w * 512 + (lg * 4 + r) * 32 + 16 + l15] = acc1[r];
        }
    }

    // ---- halo self-dots (rows 64..71) via VALU: wave 1, 8 lanes per row
    if (w == 1) {
        int r = 64 + (lane >> 3);
        int sub = lane & 7;
        float ss = 0.f;
        #pragma unroll
        for (int q = 0; q < 4; ++q) {
            int k = sub * 32 + q * 8;
            int su = k >> 3;
            bfrag v = *(const bfrag*)(x + r * 256 + ((su ^ (r & 7)) << 3));
            #pragma unroll
            for (int e = 0; e < 8; ++e) {
                float f = bf2f((unsigned short)v[e]);
                ss += f * f;
            }
        }
        ss += __shfl_xor(ss, 1);
        ss += __shfl_xor(ss, 2);
        ss += __shfl_xor(ss, 4);
        if (sub == 0) sdh[r - 64] = ss;
    }
    __syncthreads();

    // ---- scl[t] = m / (m*sqrt(selfdot) + eps)
    if (tid < 72) {
        float sd = (tid < 64) ? dotbuf[(tid >> 4) * 512 + (tid & 15) * 32 + (tid & 15)]
                              : sdh[tid - 64];
        float m = msk[tid];
        float nm = m * sqrtf(sd);
        scl[tid] = m / (nm + EPSN);
    }
    __syncthreads();

    // ---- band extraction + bf16 pack (threads 0..63 = rows)
    if (tid < RB) {
        int t = tid, wq = t >> 4, r = t & 15;
        float m_t = msk[t], sc_t = scl[t];
        ushort8_t o0, o1;
        #pragma unroll
        for (int e = 0; e < 8; ++e) { o0[e] = 0; o1[e] = 0; }
        #pragma unroll
        for (int a = 0; a <= 8; ++a) {
            float dot = dotbuf[wq * 512 + r * 32 + r + a];
            float dn = dot * sc_t * scl[t + a];
            float s = (dn - (a == 0 ? DS_ : 0.f) + 1.f) * 0.5f * m_t * msk[t + a];
            if (a < 8) o0[a] = f2bf(s); else o1[0] = f2bf(s);
        }
        unsigned short* dst = s16g + ((size_t)mb * T_ + t0 + t) * 16;
        *(ushort8_t*)dst = o0;
        *(ushort8_t*)(dst + 8) = o1;
    }
}

// ===================== Kernel B: MFMA conv stack + masked GAP partials =====================
#define TT 128
#define G_ 16
#define WB 160            // TT + 2*G_
#define SBP 24            // sbuf pitch (48B rows: 16B-aligned, conflict-free)
#define OFF_BUFA 8192
#define OFF_BUFB 28672
#define OFF_MLD  49664
#define OFF_RED  50176
#define SMEM_TOT (OFF_RED + 1024)

// swizzled ushort index: 16B slot su (0..7) of row, XOR'd by row&7; off = ushort offset in slot
static __device__ __forceinline__ int swzi(int row, int su, int off) {
    return row * 64 + ((su ^ (row & 7)) << 3) + off;
}

template<int DIL>
static __device__ __forceinline__ void conv_stage(
    const unsigned short* __restrict__ wdg, const unsigned short* __restrict__ wpg,
    unsigned short* __restrict__ bufIn, unsigned short* __restrict__ bufOut,
    const float* __restrict__ b_d, const float* __restrict__ b_p,
    int t0, int l15, int lg, int mt0, int wn)
{
    // ---- dilated 3-tap conv as K=192 GEMM (k = tap*64 + ci), bufIn -> bufOut
    {
        bfrag ad[2][6];
        float bd[2][4];
        #pragma unroll
        for (int m = 0; m < 2; ++m) {
            int row = (mt0 + m) * 16 + l15;
            #pragma unroll
            for (int ks = 0; ks < 6; ++ks) {
                int tap = ks >> 1, half = ks & 1;
                ad[m][ks] = *(const bfrag*)(wdg + row * 192 + tap * 64 + half * 32 + lg * 8);
            }
            #pragma unroll
            for (int r = 0; r < 4; ++r) bd[m][r] = b_d[(mt0 + m) * 16 + lg * 4 + r];
        }
        for (int nt = wn * 5; nt < wn * 5 + 5; ++nt) {
            int j = nt * 16 + l15;
            f32x4 acc0 = {0.f, 0.f, 0.f, 0.f}, acc1 = {0.f, 0.f, 0.f, 0.f};
            #pragma unroll
            for (int ks = 0; ks < 6; ++ks) {
                int tap = ks >> 1, half = ks & 1;
                int brow = j + (tap - 1) * DIL;
                bfrag bv = *(const bfrag*)(bufIn + swzi(brow, half * 4 + lg, 0));
                acc0 = mfma_bf16(ad[0][ks], bv, acc0);
                acc1 = mfma_bf16(ad[1][ks], bv, acc1);
            }
            int tg = t0 - G_ + j;
            bool valid = (tg >= 0 && tg < T_);
            #pragma unroll
            for (int m = 0; m < 2; ++m) {
                f32x4 acc = m ? acc1 : acc0;
                ushort4_t pk;
                #pragma unroll
                for (int r = 0; r < 4; ++r) {
                    float v = acc[r] + bd[m][r];
                    v = valid ? fmaxf(v, 0.f) : 0.f;
                    pk[r] = f2bf(v);
                }
                *(ushort4_t*)(bufOut + swzi(j, (mt0 + m) * 2 + (lg >> 1), (lg & 1) * 4)) = pk;
            }
        }
    }
    __syncthreads();

    // ---- pointwise conv as K=64 GEMM, bufOut -> bufIn
    {
        bfrag ap[2][2];
        float bpv[2][4];
        #pragma unroll
        for (int m = 0; m < 2; ++m) {
            int row = (mt0 + m) * 16 + l15;
            #pragma unroll
            for (int half = 0; half < 2; ++half)
                ap[m][half] = *(const bfrag*)(wpg + row * 64 + half * 32 + lg * 8);
            #pragma unroll
            for (int r = 0; r < 4; ++r) bpv[m][r] = b_p[(mt0 + m) * 16 + lg * 4 + r];
        }
        for (int nt = wn * 5; nt < wn * 5 + 5; ++nt) {
            int j = nt * 16 + l15;
            f32x4 acc0 = {0.f, 0.f, 0.f, 0.f}, acc1 = {0.f, 0.f, 0.f, 0.f};
            #pragma unroll
            for (int half = 0; half < 2; ++half) {
                bfrag bv = *(const bfrag*)(bufOut + swzi(j, half * 4 + lg, 0));
                acc0 = mfma_bf16(ap[0][half], bv, acc0);
                acc1 = mfma_bf16(ap[1][half], bv, acc1);
            }
            int tg = t0 - G_ + j;
            bool valid = (tg >= 0 && tg < T_);
            #pragma unroll
            for (int m = 0; m < 2; ++m) {
                f32x4 acc = m ? acc1 : acc0;
                ushort4_t pk;
                #pragma unroll
                for (int r = 0; r < 4; ++r) {
                    float v = acc[r] + bpv[m][r];
                    v = valid ? fmaxf(v, 0.f) : 0.f;
                    pk[r] = f2bf(v);
                }
                *(ushort4_t*)(bufIn + swzi(j, (mt0 + m) * 2 + (lg >> 1), (lg & 1) * 4)) = pk;
            }
        }
    }
    __syncthreads();
}

__global__ __launch_bounds__(256, 3) void conv_mfma_kernel(
    const unsigned short* __restrict__ s16g,
    const float* __restrict__ mask0, const float* __restrict__ mask1,
    const unsigned short* __restrict__ wk,
    const float* __restrict__ b_in,
    const float* __restrict__ b_d1, const float* __restrict__ b_p1,
    const float* __restrict__ b_d2, const float* __restrict__ b_p2,
    const float* __restrict__ b_d3, const float* __restrict__ b_p3,
    float* __restrict__ z_part)        // [2*B][32][64]
{
    __shared__ __align__(16) char smem[SMEM_TOT];
    unsigned short* sbuf = (unsigned short*)smem;                 // [WB][SBP]
    unsigned short* bufA = (unsigned short*)(smem + OFF_BUFA);
    unsigned short* bufB = (unsigned short*)(smem + OFF_BUFB);
    float* mld = (float*)(smem + OFF_MLD);                        // [TT]
    float* red = (float*)(smem + OFF_RED);                        // [4][64]

    int bid  = blockIdx.x;                             // 2*B*32 = 2048
    int tile = bid & 31;
    int b    = (bid >> 5) & 31;
    int mod  = bid >> 10;
    int mb   = mod * B_ + b;
    const float* mask = mod ? mask1 : mask0;
    int t0  = tile * TT;
    int tid = threadIdx.x;
    int lane = tid & 63;
    int w = tid >> 6;
    int l15 = lane & 15, lg = lane >> 4;
    int wm = w >> 1, wn = w & 1;
    int mt0 = wm * 2;

    const unsigned short* weff_g = wk;

    // ---- stage s16 tile (with t-bounds zero fill) + mask
    {
        const unsigned short* srow = s16g + (size_t)mb * T_ * 16;
        for (int ch = tid; ch < WB * 2; ch += 256) {
            int j = ch >> 1, q = ch & 1;
            int t = t0 - G_ + j;
            ushort8_t v = {0, 0, 0, 0, 0, 0, 0, 0};
            if (t >= 0 && t < T_) v = *(const ushort8_t*)(srow + (size_t)t * 16 + q * 8);
            *(ushort8_t*)(sbuf + j * SBP + q * 8) = v;
        }
        if (tid < TT) {
            int tg = t0 + tid;
            mld[tid] = (tg < T_) ? mask[(size_t)b * T_ + tg] : 0.f;
        }
    }
    __syncthreads();

    // ---- in-conv (K=9 padded into one masked K=32 MFMA step) -> bufA
    {
        int lg2 = lg & 1;
        bfrag a_in[2];
        float bi[2][4];
        #pragma unroll
        for (int m = 0; m < 2; ++m) {
            int row = (mt0 + m) * 16 + l15;
            a_in[m] = *(const bfrag*)(weff_g + row * 16 + lg2 * 8);
            #pragma unroll
            for (int r = 0; r < 4; ++r) bi[m][r] = b_in[(mt0 + m) * 16 + lg * 4 + r];
        }
        for (int nt = wn * 5; nt < wn * 5 + 5; ++nt) {
            int j = nt * 16 + l15;
            bfrag bv = {0, 0, 0, 0, 0, 0, 0, 0};
            if (lg < 2) bv = *(const bfrag*)(sbuf + j * SBP + lg * 8);
            f32x4 acc0 = {0.f, 0.f, 0.f, 0.f}, acc1 = {0.f, 0.f, 0.f, 0.f};
            acc0 = mfma_bf16(a_in[0], bv, acc0);
            acc1 = mfma_bf16(a_in[1], bv, acc1);
            int tg = t0 - G_ + j;
            bool valid = (tg >= 0 && tg < T_);
            #pragma unroll
            for (int m = 0; m < 2; ++m) {
                f32x4 acc = m ? acc1 : acc0;
                ushort4_t pk;
                #pragma unroll
                for (int r = 0; r < 4; ++r) {
                    float v = acc[r] + bi[m][r];
                    v = valid ? fmaxf(v, 0.f) : 0.f;
                    pk[r] = f2bf(v);
                }
                *(ushort4_t*)(bufA + swzi(j, (mt0 + m) * 2 + (lg >> 1), (lg & 1) * 4)) = pk;
            }
        }
    }
    __syncthreads();

    conv_stage<1>(wk + 1024,             wk + 1024 + 12288,             bufA, bufB, b_d1, b_p1, t0, l15, lg, mt0, wn);
    conv_stage<2>(wk + 1024 + 16384,     wk + 1024 + 16384 + 12288,     bufA, bufB, b_d2, b_p2, t0, l15, lg, mt0, wn);
    conv_stage<4>(wk + 1024 + 2 * 16384, wk + 1024 + 2 * 16384 + 12288, bufA, bufB, b_d3, b_p3, t0, l15, lg, mt0, wn);

    // ---- masked GAP partial over this tile's 128 cols (j in [G_, G_+TT))
    {
        int c = tid & 63, g = tid >> 6;
        float acc = 0.f;
        #pragma unroll 4
        for (int i = 0; i < 32; ++i) {
            int jj = g * 32 + i;
            int r = G_ + jj;
            acc += bf2f(bufA[swzi(r, c >> 3, c & 7)]) * mld[jj];
        }
        red[g * 64 + c] = acc;
    }
    __syncthreads();
    if (tid < 64) {
        float z = red[tid] + red[64 + tid] + red[128 + tid] + red[192 + tid];
        z_part[((size_t)mb * 32 + tile) * 64 + tid] = z;
    }
}

// ===================== Kernel C: GAP divide + LayerNorm + gates =====================
__global__ __launch_bounds__(128) void gates_kernel(
    const float* __restrict__ z_part,
    const float* __restrict__ mask0, const float* __restrict__ mask1,
    const float* __restrict__ ln_g, const float* __restrict__ ln_b,
    const float* __restrict__ mha_w1, const float* __restrict__ mha_b1,
    const float* __restrict__ mha_w2, const float* __restrict__ mha_b2,
    const float* __restrict__ ffn_w1, const float* __restrict__ ffn_b1,
    const float* __restrict__ ffn_w2, const float* __restrict__ ffn_b2,
    float* __restrict__ out)
{
    __shared__ float fn[128];
    __shared__ float red[4];
    __shared__ float msum[2];
    int b = blockIdx.x, tid = threadIdx.x;
    int mod = tid >> 6, c = tid & 63;

    float z = 0.f;
    for (int tl = 0; tl < 32; ++tl)
        z += z_part[((size_t)(mod * B_ + b) * 32 + tl) * 64 + c];

    const float* mk = mod ? mask1 : mask0;
    float ms = 0.f;
    for (int t = c; t < T_; t += 64) ms += mk[(size_t)b * T_ + t];
    #pragma unroll
    for (int o = 32; o > 0; o >>= 1) ms += __shfl_xor(ms, o);
    if (c == 0) msum[mod] = ms;
    __syncthreads();

    float fv = z / (msum[mod] + EPSG);
    float s1 = fv, s2 = fv * fv;
    #pragma unroll
    for (int o = 32; o > 0; o >>= 1) { s1 += __shfl_xor(s1, o); s2 += __shfl_xor(s2, o); }
    if (c == 0) { red[mod * 2] = s1; red[mod * 2 + 1] = s2; }
    __syncthreads();

    float mu  = (red[0] + red[2]) * (1.0f / 128.0f);
    float ex2 = (red[1] + red[3]) * (1.0f / 128.0f);
    float var = ex2 - mu * mu;
    float fnv = (fv - mu) * rsqrtf(var + EPSL) * ln_g[tid] + ln_b[tid];
    fn[tid] = fnv;
    __syncthreads();

    const float* W1 = mod ? ffn_w1 : mha_w1;
    const float* B1 = mod ? ffn_b1 : mha_b1;
    const float* W2 = mod ? ffn_w2 : mha_w2;
    const float* B2 = mod ? ffn_b2 : mha_b2;
    float r = B1[c];
    for (int i = 0; i < 128; ++i) r += fn[i] * W1[i * 64 + c];
    r = fmaxf(r, 0.f);
    float g = r * W2[c];
    #pragma unroll
    for (int o = 32; o > 0; o >>= 1) g += __shfl_xor(g, o);
    if (c == 0) {
        g += B2[0];
        out[mod * B_ + b] = mod ? tanhf(g) : 1.0f / (1.0f + expf(-g));
    }
}

// ===================== launch =====================
extern "C" void kernel_launch(void* const* d_in, const int* in_sizes, int n_in,
                              void* d_out, int out_size, void* d_ws, size_t ws_size,
                              hipStream_t stream) {
    const float* video_feat = (const float*)d_in[0];
    const float* audio_feat = (const float*)d_in[1];
    const float* video_mask = (const float*)d_in[2];
    const float* audio_mask = (const float*)d_in[3];
    const float* w_in = (const float*)d_in[4];
    const float* b_in = (const float*)d_in[5];
    const float* w_d1 = (const float*)d_in[6];
    const float* b_d1 = (const float*)d_in[7];
    const float* w_p1 = (const float*)d_in[8];
    const float* b_p1 = (const float*)d_in[9];
    const float* w_d2 = (const float*)d_in[10];
    const float* b_d2 = (const float*)d_in[11];
    const float* w_p2 = (const float*)d_in[12];
    const float* b_p2 = (const float*)d_in[13];
    const float* w_d3 = (const float*)d_in[14];
    const float* b_d3 = (const float*)d_in[15];
    const float* w_p3 = (const float*)d_in[16];
    const float* b_p3 = (const float*)d_in[17];
    const float* ln_g = (const float*)d_in[18];
    const float* ln_b = (const float*)d_in[19];
    const float* mha_w1 = (const float*)d_in[20];
    const float* mha_b1 = (const float*)d_in[21];
    const float* mha_w2 = (const float*)d_in[22];
    const float* mha_b2 = (const float*)d_in[23];
    const float* ffn_w1 = (const float*)d_in[24];
    const float* ffn_b1 = (const float*)d_in[25];
    const float* ffn_w2 = (const float*)d_in[26];
    const float* ffn_b2 = (const float*)d_in[27];

    unsigned short* s16g = (unsigned short*)d_ws;                          // 2*B*T*16 bf16 = 8.39 MB
    float* z_part = (float*)((char*)d_ws + (size_t)2 * B_ * T_ * 16 * 2);  // 2*B*32*64 f32 = 512 KB
    unsigned short* wk = (unsigned short*)((char*)z_part + (size_t)2 * B_ * 32 * 64 * 4);  // 100 KB

    prepack_kernel<<<dim3(196), dim3(256), 0, stream>>>(
        w_in, w_d1, w_p1, w_d2, w_p2, w_d3, w_p3, wk);

    strip_kernel<<<dim3(2 * B_ * (T_ / RB)), dim3(256), 0, stream>>>(
        audio_feat, audio_mask, video_feat, video_mask, s16g);

    conv_mfma_kernel<<<dim3(2 * B_ * (T_ / TT)), dim3(256), 0, stream>>>(
        s16g, audio_mask, video_mask, wk, b_in,
        b_d1, b_p1, b_d2, b_p2, b_d3, b_p3, z_part);

    gates_kernel<<<dim3(B_), dim3(128), 0, stream>>>(
        z_part, audio_mask, video_mask, ln_g, ln_b,
        mha_w1, mha_b1, mha_w2, mha_b2, ffn_w1, ffn_b1, ffn_w2, ffn_b2,
        (float*)d_out);
}

// Round 5
// 163.289 us; speedup vs baseline: 9.7973x; 1.0763x over previous
//
#include <hip/hip_runtime.h>
#include <math.h>

#define B_ 32
#define T_ 4096
#define D_ 256
#define C_ 64
#define EPSN 1e-6f
#define EPSG 1e-6f
#define EPSL 1e-5f
#define DS_ 0.1f

typedef short bfrag __attribute__((ext_vector_type(8)));      // 8 bf16 = 4 VGPR
typedef float f32x4 __attribute__((ext_vector_type(4)));
typedef unsigned short ushort4_t __attribute__((ext_vector_type(4)));
typedef unsigned short ushort8_t __attribute__((ext_vector_type(8)));

static __device__ __forceinline__ unsigned short f2bf(float f) {
    unsigned int u = __builtin_bit_cast(unsigned int, f);
    unsigned int r = u + 0x7fffu + ((u >> 16) & 1u);
    return (unsigned short)(r >> 16);
}
static __device__ __forceinline__ float bf2f(unsigned short u) {
    return __builtin_bit_cast(float, ((unsigned int)u) << 16);
}

static __device__ __forceinline__ f32x4 mfma_bf16(bfrag a, bfrag b, f32x4 c) {
    return __builtin_amdgcn_mfma_f32_16x16x32_bf16(a, b, c, 0, 0, 0);
}

// ===================== Kernel P: prepack weights -> bf16 fragment-layout images =====================
__global__ __launch_bounds__(256) void prepack_kernel(
    const float* __restrict__ w_in,
    const float* __restrict__ wd0, const float* __restrict__ wp0,
    const float* __restrict__ wd1, const float* __restrict__ wp1,
    const float* __restrict__ wd2, const float* __restrict__ wp2,
    unsigned short* __restrict__ wk)
{
    int idx = blockIdx.x * 256 + threadIdx.x;
    if (idx >= 1024 + 3 * 16384) return;
    if (idx < 1024) {
        int c = idx >> 4, a = idx & 15;
        float wv = 0.f;
        if (a <= 8) {
            wv = w_in[c * 17 + 8 + a];
            if (a > 0) wv += w_in[c * 17 + 8 - a];
        }
        wk[idx] = f2bf(wv);
    } else {
        int i2 = idx - 1024;
        int s = i2 >> 14;
        int r = i2 & 16383;
        const float* wd = s == 0 ? wd0 : (s == 1 ? wd1 : wd2);
        const float* wp = s == 0 ? wp0 : (s == 1 ? wp1 : wp2);
        unsigned short v;
        if (r < 12288) {
            int c = r / 192, k = r - c * 192;
            int tap = k >> 6, ci = k & 63;
            v = f2bf(wd[c * 192 + ci * 3 + tap]);
        } else {
            v = f2bf(wp[r - 12288]);
        }
        wk[idx] = v;
    }
}

// ===================== Kernel A: MFMA Gram-band strip, global-direct fragments =====================
// Block: 256 thr (4 waves), RB=64 output rows. No X staging: each wave builds A/B frags
// straight from global f32 (L2 serves the wave-to-wave row overlap). Per wave:
// tile0 = (rows r0..r0+15) x (same), tile1 = x (rows r0+16..r0+31), K=256.
#define RB 64
#define DBP 33     // dotbuf row pitch (f32) -> conflict-free

__global__ __launch_bounds__(256, 4) void strip_kernel(
    const float* __restrict__ feat0, const float* __restrict__ mask0,
    const float* __restrict__ feat1, const float* __restrict__ mask1,
    unsigned short* __restrict__ s16g)     // [2*B][T][16] bf16, slots 0..8 = bands, 9..15 = 0
{
    __shared__ float dotbuf[4 * 16 * DBP];       // per-wave 16x32 raw dots (pitch 33)
    __shared__ float scl[72];
    __shared__ float msk[72];
    __shared__ float sdh[8];                     // halo self-dots rows 64..71

    int bid  = blockIdx.x;            // 2*B*64 = 4096
    int tile = bid & 63;
    int b    = (bid >> 6) & 31;
    int mod  = bid >> 11;
    int mb   = mod * B_ + b;
    const float* feat = mod ? feat1 : feat0;
    const float* mask = mod ? mask1 : mask0;
    int t0 = tile * RB;
    int tid = threadIdx.x;
    int w = tid >> 6, lane = tid & 63;
    int l15 = lane & 15, lg = lane >> 4;

    if (tid < 72) {
        int tg = t0 + tid;
        msk[tid] = (tg < T_) ? mask[(size_t)b * T_ + tg] : 0.f;
    }

    // ---- Gram tiles via MFMA, fragments direct from global
    {
        int tA = t0 + w * 16 + l15;          // always < T_
        int tB = tA + 16;
        bool okB = (tB < T_);
        const float* baseA = feat + ((size_t)b * T_ + tA) * D_ + lg * 8;
        const float* baseB = feat + ((size_t)b * T_ + (okB ? tB : 0)) * D_ + lg * 8;
        f32x4 acc0 = {0.f, 0.f, 0.f, 0.f}, acc1 = {0.f, 0.f, 0.f, 0.f};
        #pragma unroll
        for (int ks = 0; ks < 8; ++ks) {
            float4 al = *(const float4*)(baseA + ks * 32);
            float4 ah = *(const float4*)(baseA + ks * 32 + 4);
            float4 bl = okB ? *(const float4*)(baseB + ks * 32)     : make_float4(0.f, 0.f, 0.f, 0.f);
            float4 bh = okB ? *(const float4*)(baseB + ks * 32 + 4) : make_float4(0.f, 0.f, 0.f, 0.f);
            bfrag av, bv;
            av[0] = (short)f2bf(al.x); av[1] = (short)f2bf(al.y);
            av[2] = (short)f2bf(al.z); av[3] = (short)f2bf(al.w);
            av[4] = (short)f2bf(ah.x); av[5] = (short)f2bf(ah.y);
            av[6] = (short)f2bf(ah.z); av[7] = (short)f2bf(ah.w);
            bv[0] = (short)f2bf(bl.x); bv[1] = (short)f2bf(bl.y);
            bv[2] = (short)f2bf(bl.z); bv[3] = (short)f2bf(bl.w);
            bv[4] = (short)f2bf(bh.x); bv[5] = (short)f2bf(bh.y);
            bv[6] = (short)f2bf(bh.z); bv[7] = (short)f2bf(bh.w);
            acc0 = mfma_bf16(av, av, acc0);
            acc1 = mfma_bf16(av, bv, acc1);
        }
        #pragma unroll
        for (int r = 0; r < 4; ++r) {
            dotbuf[w * 16 * DBP + (lg * 4 + r) * DBP + l15] = acc0[r];
            dotbuf[w * 16 * DBP + (lg * 4 + r) * DBP + 16 + l15] = acc1[r];
        }
    }

    // ---- halo self-dots (local rows 64..71): wave w handles rows 64+2w, 64+2w+1; 32 lanes/row
    {
        int l5 = lane & 31;
        int r = 64 + w * 2 + (lane >> 5);
        int tg = t0 + r;
        float ss = 0.f;
        if (tg < T_) {
            const float* p = feat + ((size_t)b * T_ + tg) * D_ + l5 * 8;
            float4 v0 = *(const float4*)(p);
            float4 v1 = *(const float4*)(p + 4);
            float f;
            f = bf2f(f2bf(v0.x)); ss += f * f;
            f = bf2f(f2bf(v0.y)); ss += f * f;
            f = bf2f(f2bf(v0.z)); ss += f * f;
            f = bf2f(f2bf(v0.w)); ss += f * f;
            f = bf2f(f2bf(v1.x)); ss += f * f;
            f = bf2f(f2bf(v1.y)); ss += f * f;
            f = bf2f(f2bf(v1.z)); ss += f * f;
            f = bf2f(f2bf(v1.w)); ss += f * f;
        }
        ss += __shfl_xor(ss, 1);
        ss += __shfl_xor(ss, 2);
        ss += __shfl_xor(ss, 4);
        ss += __shfl_xor(ss, 8);
        ss += __shfl_xor(ss, 16);
        if (l5 == 0) sdh[r - 64] = ss;
    }
    __syncthreads();

    // ---- scl[t] = m / (m*sqrt(selfdot) + eps), t in [0,72)
    if (tid < 72) {
        float sd = (tid < 64) ? dotbuf[(tid >> 4) * 16 * DBP + (tid & 15) * DBP + (tid & 15)]
                              : sdh[tid - 64];
        float m = msk[tid];
        float nm = m * sqrtf(sd);
        scl[tid] = m / (nm + EPSN);
    }
    __syncthreads();

    // ---- band extraction + bf16 pack (threads 0..63 = rows)
    if (tid < RB) {
        int t = tid, wq = t >> 4, r = t & 15;
        float m_t = msk[t], sc_t = scl[t];
        ushort8_t o0, o1;
        #pragma unroll
        for (int e = 0; e < 8; ++e) { o0[e] = 0; o1[e] = 0; }
        #pragma unroll
        for (int a = 0; a <= 8; ++a) {
            float dot = dotbuf[wq * 16 * DBP + r * DBP + r + a];
            float dn = dot * sc_t * scl[t + a];
            float s = (dn - (a == 0 ? DS_ : 0.f) + 1.f) * 0.5f * m_t * msk[t + a];
            if (a < 8) o0[a] = f2bf(s); else o1[0] = f2bf(s);
        }
        unsigned short* dst = s16g + ((size_t)mb * T_ + t0 + t) * 16;
        *(ushort8_t*)dst = o0;
        *(ushort8_t*)(dst + 8) = o1;
    }
}

// ===================== Kernel B: MFMA conv stack + masked GAP partials =====================
#define TT 128
#define G_ 16
#define WB 160            // TT + 2*G_
#define SBP 24            // sbuf pitch (48B rows: 16B-aligned, conflict-free)
#define OFF_BUFA 8192
#define OFF_BUFB 28672
#define OFF_MLD  49664
#define OFF_RED  50176
#define SMEM_TOT (OFF_RED + 1024)

// swizzled ushort index: 16B slot su (0..7) of row, XOR'd by row&7; off = ushort offset in slot
static __device__ __forceinline__ int swzi(int row, int su, int off) {
    return row * 64 + ((su ^ (row & 7)) << 3) + off;
}

template<int DIL>
static __device__ __forceinline__ void conv_stage(
    const unsigned short* __restrict__ wdg, const unsigned short* __restrict__ wpg,
    unsigned short* __restrict__ bufIn, unsigned short* __restrict__ bufOut,
    const float* __restrict__ b_d, const float* __restrict__ b_p,
    int t0, int l15, int lg, int mt0, int wn)
{
    // ---- dilated 3-tap conv as K=192 GEMM (k = tap*64 + ci), bufIn -> bufOut
    {
        bfrag ad[2][6];
        float bd[2][4];
        #pragma unroll
        for (int m = 0; m < 2; ++m) {
            int row = (mt0 + m) * 16 + l15;
            #pragma unroll
            for (int ks = 0; ks < 6; ++ks) {
                int tap = ks >> 1, half = ks & 1;
                ad[m][ks] = *(const bfrag*)(wdg + row * 192 + tap * 64 + half * 32 + lg * 8);
            }
            #pragma unroll
            for (int r = 0; r < 4; ++r) bd[m][r] = b_d[(mt0 + m) * 16 + lg * 4 + r];
        }
        for (int nt = wn * 5; nt < wn * 5 + 5; ++nt) {
            int j = nt * 16 + l15;
            f32x4 acc0 = {0.f, 0.f, 0.f, 0.f}, acc1 = {0.f, 0.f, 0.f, 0.f};
            #pragma unroll
            for (int ks = 0; ks < 6; ++ks) {
                int tap = ks >> 1, half = ks & 1;
                int brow = j + (tap - 1) * DIL;
                bfrag bv = *(const bfrag*)(bufIn + swzi(brow, half * 4 + lg, 0));
                acc0 = mfma_bf16(ad[0][ks], bv, acc0);
                acc1 = mfma_bf16(ad[1][ks], bv, acc1);
            }
            int tg = t0 - G_ + j;
            bool valid = (tg >= 0 && tg < T_);
            #pragma unroll
            for (int m = 0; m < 2; ++m) {
                f32x4 acc = m ? acc1 : acc0;
                ushort4_t pk;
                #pragma unroll
                for (int r = 0; r < 4; ++r) {
                    float v = acc[r] + bd[m][r];
                    v = valid ? fmaxf(v, 0.f) : 0.f;
                    pk[r] = f2bf(v);
                }
                *(ushort4_t*)(bufOut + swzi(j, (mt0 + m) * 2 + (lg >> 1), (lg & 1) * 4)) = pk;
            }
        }
    }
    __syncthreads();

    // ---- pointwise conv as K=64 GEMM, bufOut -> bufIn
    {
        bfrag ap[2][2];
        float bpv[2][4];
        #pragma unroll
        for (int m = 0; m < 2; ++m) {
            int row = (mt0 + m) * 16 + l15;
            #pragma unroll
            for (int half = 0; half < 2; ++half)
                ap[m][half] = *(const bfrag*)(wpg + row * 64 + half * 32 + lg * 8);
            #pragma unroll
            for (int r = 0; r < 4; ++r) bpv[m][r] = b_p[(mt0 + m) * 16 + lg * 4 + r];
        }
        for (int nt = wn * 5; nt < wn * 5 + 5; ++nt) {
            int j = nt * 16 + l15;
            f32x4 acc0 = {0.f, 0.f, 0.f, 0.f}, acc1 = {0.f, 0.f, 0.f, 0.f};
            #pragma unroll
            for (int half = 0; half < 2; ++half) {
                bfrag bv = *(const bfrag*)(bufOut + swzi(j, half * 4 + lg, 0));
                acc0 = mfma_bf16(ap[0][half], bv, acc0);
                acc1 = mfma_bf16(ap[1][half], bv, acc1);
            }
            int tg = t0 - G_ + j;
            bool valid = (tg >= 0 && tg < T_);
            #pragma unroll
            for (int m = 0; m < 2; ++m) {
                f32x4 acc = m ? acc1 : acc0;
                ushort4_t pk;
                #pragma unroll
                for (int r = 0; r < 4; ++r) {
                    float v = acc[r] + bpv[m][r];
                    v = valid ? fmaxf(v, 0.f) : 0.f;
                    pk[r] = f2bf(v);
                }
                *(ushort4_t*)(bufIn + swzi(j, (mt0 + m) * 2 + (lg >> 1), (lg & 1) * 4)) = pk;
            }
        }
    }
    __syncthreads();
}

__global__ __launch_bounds__(256, 3) void conv_mfma_kernel(
    const unsigned short* __restrict__ s16g,
    const float* __restrict__ mask0, const float* __restrict__ mask1,
    const unsigned short* __restrict__ wk,
    const float* __restrict__ b_in,
    const float* __restrict__ b_d1, const float* __restrict__ b_p1,
    const float* __restrict__ b_d2, const float* __restrict__ b_p2,
    const float* __restrict__ b_d3, const float* __restrict__ b_p3,
    float* __restrict__ z_part)        // [2*B][32][64]
{
    __shared__ __align__(16) char smem[SMEM_TOT];
    unsigned short* sbuf = (unsigned short*)smem;                 // [WB][SBP]
    unsigned short* bufA = (unsigned short*)(smem + OFF_BUFA);
    unsigned short* bufB = (unsigned short*)(smem + OFF_BUFB);
    float* mld = (float*)(smem + OFF_MLD);                        // [TT]
    float* red = (float*)(smem + OFF_RED);                        // [4][64]

    int bid  = blockIdx.x;                             // 2*B*32 = 2048
    int tile = bid & 31;
    int b    = (bid >> 5) & 31;
    int mod  = bid >> 10;
    int mb   = mod * B_ + b;
    const float* mask = mod ? mask1 : mask0;
    int t0  = tile * TT;
    int tid = threadIdx.x;
    int lane = tid & 63;
    int w = tid >> 6;
    int l15 = lane & 15, lg = lane >> 4;
    int wm = w >> 1, wn = w & 1;
    int mt0 = wm * 2;

    const unsigned short* weff_g = wk;

    // ---- stage s16 tile (with t-bounds zero fill) + mask
    {
        const unsigned short* srow = s16g + (size_t)mb * T_ * 16;
        for (int ch = tid; ch < WB * 2; ch += 256) {
            int j = ch >> 1, q = ch & 1;
            int t = t0 - G_ + j;
            ushort8_t v = {0, 0, 0, 0, 0, 0, 0, 0};
            if (t >= 0 && t < T_) v = *(const ushort8_t*)(srow + (size_t)t * 16 + q * 8);
            *(ushort8_t*)(sbuf + j * SBP + q * 8) = v;
        }
        if (tid < TT) {
            int tg = t0 + tid;
            mld[tid] = (tg < T_) ? mask[(size_t)b * T_ + tg] : 0.f;
        }
    }
    __syncthreads();

    // ---- in-conv (K=9 padded into one masked K=32 MFMA step) -> bufA
    {
        int lg2 = lg & 1;
        bfrag a_in[2];
        float bi[2][4];
        #pragma unroll
        for (int m = 0; m < 2; ++m) {
            int row = (mt0 + m) * 16 + l15;
            a_in[m] = *(const bfrag*)(weff_g + row * 16 + lg2 * 8);
            #pragma unroll
            for (int r = 0; r < 4; ++r) bi[m][r] = b_in[(mt0 + m) * 16 + lg * 4 + r];
        }
        for (int nt = wn * 5; nt < wn * 5 + 5; ++nt) {
            int j = nt * 16 + l15;
            bfrag bv = {0, 0, 0, 0, 0, 0, 0, 0};
            if (lg < 2) bv = *(const bfrag*)(sbuf + j * SBP + lg * 8);
            f32x4 acc0 = {0.f, 0.f, 0.f, 0.f}, acc1 = {0.f, 0.f, 0.f, 0.f};
            acc0 = mfma_bf16(a_in[0], bv, acc0);
            acc1 = mfma_bf16(a_in[1], bv, acc1);
            int tg = t0 - G_ + j;
            bool valid = (tg >= 0 && tg < T_);
            #pragma unroll
            for (int m = 0; m < 2; ++m) {
                f32x4 acc = m ? acc1 : acc0;
                ushort4_t pk;
                #pragma unroll
                for (int r = 0; r < 4; ++r) {
                    float v = acc[r] + bi[m][r];
                    v = valid ? fmaxf(v, 0.f) : 0.f;
                    pk[r] = f2bf(v);
                }
                *(ushort4_t*)(bufA + swzi(j, (mt0 + m) * 2 + (lg >> 1), (lg & 1) * 4)) = pk;
            }
        }
    }
    __syncthreads();

    conv_stage<1>(wk + 1024,             wk + 1024 + 12288,             bufA, bufB, b_d1, b_p1, t0, l15, lg, mt0, wn);
    conv_stage<2>(wk + 1024 + 16384,     wk + 1024 + 16384 + 12288,     bufA, bufB, b_d2, b_p2, t0, l15, lg, mt0, wn);
    conv_stage<4>(wk + 1024 + 2 * 16384, wk + 1024 + 2 * 16384 + 12288, bufA, bufB, b_d3, b_p3, t0, l15, lg, mt0, wn);

    // ---- masked GAP partial over this tile's 128 cols (j in [G_, G_+TT))
    {
        int c = tid & 63, g = tid >> 6;
        float acc = 0.f;
        #pragma unroll 4
        for (int i = 0; i < 32; ++i) {
            int jj = g * 32 + i;
            int r = G_ + jj;
            acc += bf2f(bufA[swzi(r, c >> 3, c & 7)]) * mld[jj];
        }
        red[g * 64 + c] = acc;
    }
    __syncthreads();
    if (tid < 64) {
        float z = red[tid] + red[64 + tid] + red[128 + tid] + red[192 + tid];
        z_part[((size_t)mb * 32 + tile) * 64 + tid] = z;
    }
}

// ===================== Kernel C: GAP divide + LayerNorm + gates =====================
__global__ __launch_bounds__(128) void gates_kernel(
    const float* __restrict__ z_part,
    const float* __restrict__ mask0, const float* __restrict__ mask1,
    const float* __restrict__ ln_g, const float* __restrict__ ln_b,
    const float* __restrict__ mha_w1, const float* __restrict__ mha_b1,
    const float* __restrict__ mha_w2, const float* __restrict__ mha_b2,
    const float* __restrict__ ffn_w1, const float* __restrict__ ffn_b1,
    const float* __restrict__ ffn_w2, const float* __restrict__ ffn_b2,
    float* __restrict__ out)
{
    __shared__ float fn[128];
    __shared__ float red[4];
    __shared__ float msum[2];
    int b = blockIdx.x, tid = threadIdx.x;
    int mod = tid >> 6, c = tid & 63;

    float z = 0.f;
    for (int tl = 0; tl < 32; ++tl)
        z += z_part[((size_t)(mod * B_ + b) * 32 + tl) * 64 + c];

    const float* mk = mod ? mask1 : mask0;
    float ms = 0.f;
    for (int t = c; t < T_; t += 64) ms += mk[(size_t)b * T_ + t];
    #pragma unroll
    for (int o = 32; o > 0; o >>= 1) ms += __shfl_xor(ms, o);
    if (c == 0) msum[mod] = ms;
    __syncthreads();

    float fv = z / (msum[mod] + EPSG);
    float s1 = fv, s2 = fv * fv;
    #pragma unroll
    for (int o = 32; o > 0; o >>= 1) { s1 += __shfl_xor(s1, o); s2 += __shfl_xor(s2, o); }
    if (c == 0) { red[mod * 2] = s1; red[mod * 2 + 1] = s2; }
    __syncthreads();

    float mu  = (red[0] + red[2]) * (1.0f / 128.0f);
    float ex2 = (red[1] + red[3]) * (1.0f / 128.0f);
    float var = ex2 - mu * mu;
    float fnv = (fv - mu) * rsqrtf(var + EPSL) * ln_g[tid] + ln_b[tid];
    fn[tid] = fnv;
    __syncthreads();

    const float* W1 = mod ? ffn_w1 : mha_w1;
    const float* B1 = mod ? ffn_b1 : mha_b1;
    const float* W2 = mod ? ffn_w2 : mha_w2;
    const float* B2 = mod ? ffn_b2 : mha_b2;
    float r = B1[c];
    for (int i = 0; i < 128; ++i) r += fn[i] * W1[i * 64 + c];
    r = fmaxf(r, 0.f);
    float g = r * W2[c];
    #pragma unroll
    for (int o = 32; o > 0; o >>= 1) g += __shfl_xor(g, o);
    if (c == 0) {
        g += B2[0];
        out[mod * B_ + b] = mod ? tanhf(g) : 1.0f / (1.0f + expf(-g));
    }
}

// ===================== launch =====================
extern "C" void kernel_launch(void* const* d_in, const int* in_sizes, int n_in,
                              void* d_out, int out_size, void* d_ws, size_t ws_size,
                              hipStream_t stream) {
    const float* video_feat = (const float*)d_in[0];
    const float* audio_feat = (const float*)d_in[1];
    const float* video_mask = (const float*)d_in[2];
    const float* audio_mask = (const float*)d_in[3];
    const float* w_in = (const float*)d_in[4];
    const float* b_in = (const float*)d_in[5];
    const float* w_d1 = (const float*)d_in[6];
    const float* b_d1 = (const float*)d_in[7];
    const float* w_p1 = (const float*)d_in[8];
    const float* b_p1 = (const float*)d_in[9];
    const float* w_d2 = (const float*)d_in[10];
    const float* b_d2 = (const float*)d_in[11];
    const float* w_p2 = (const float*)d_in[12];
    const float* b_p2 = (const float*)d_in[13];
    const float* w_d3 = (const float*)d_in[14];
    const float* b_d3 = (const float*)d_in[15];
    const float* w_p3 = (const float*)d_in[16];
    const float* b_p3 = (const float*)d_in[17];
    const float* ln_g = (const float*)d_in[18];
    const float* ln_b = (const float*)d_in[19];
    const float* mha_w1 = (const float*)d_in[20];
    const float* mha_b1 = (const float*)d_in[21];
    const float* mha_w2 = (const float*)d_in[22];
    const float* mha_b2 = (const float*)d_in[23];
    const float* ffn_w1 = (const float*)d_in[24];
    const float* ffn_b1 = (const float*)d_in[25];
    const float* ffn_w2 = (const float*)d_in[26];
    const float* ffn_b2 = (const float*)d_in[27];

    unsigned short* s16g = (unsigned short*)d_ws;                          // 2*B*T*16 bf16 = 8.39 MB
    float* z_part = (float*)((char*)d_ws + (size_t)2 * B_ * T_ * 16 * 2);  // 2*B*32*64 f32 = 512 KB
    unsigned short* wk = (unsigned short*)((char*)z_part + (size_t)2 * B_ * 32 * 64 * 4);  // 100 KB

    prepack_kernel<<<dim3(196), dim3(256), 0, stream>>>(
        w_in, w_d1, w_p1, w_d2, w_p2, w_d3, w_p3, wk);

    strip_kernel<<<dim3(2 * B_ * (T_ / RB)), dim3(256), 0, stream>>>(
        audio_feat, audio_mask, video_feat, video_mask, s16g);

    conv_mfma_kernel<<<dim3(2 * B_ * (T_ / TT)), dim3(256), 0, stream>>>(
        s16g, audio_mask, video_mask, wk, b_in,
        b_d1, b_p1, b_d2, b_p2, b_d3, b_p3, z_part);

    gates_kernel<<<dim3(B_), dim3(128), 0, stream>>>(
        z_part, audio_mask, video_mask, ln_g, ln_b,
        mha_w1, mha_b1, mha_w2, mha_b2, ffn_w1, ffn_b1, ffn_w2, ffn_b2,
        (float*)d_out);
}

// Round 6
// 143.853 us; speedup vs baseline: 11.1210x; 1.1351x over previous
//
#include <hip/hip_runtime.h>
#include <math.h>

#define B_ 32
#define T_ 4096
#define D_ 256
#define C_ 64
#define EPSN 1e-6f
#define EPSG 1e-6f
#define EPSL 1e-5f
#define DS_ 0.1f

typedef short bfrag __attribute__((ext_vector_type(8)));      // 8 bf16 = 4 VGPR
typedef float f32x4 __attribute__((ext_vector_type(4)));
typedef unsigned short ushort4_t __attribute__((ext_vector_type(4)));
typedef unsigned short ushort8_t __attribute__((ext_vector_type(8)));

static __device__ __forceinline__ unsigned short f2bf(float f) {
    unsigned int u = __builtin_bit_cast(unsigned int, f);
    unsigned int r = u + 0x7fffu + ((u >> 16) & 1u);
    return (unsigned short)(r >> 16);
}
static __device__ __forceinline__ float bf2f(unsigned short u) {
    return __builtin_bit_cast(float, ((unsigned int)u) << 16);
}

static __device__ __forceinline__ f32x4 mfma_bf16(bfrag a, bfrag b, f32x4 c) {
    return __builtin_amdgcn_mfma_f32_16x16x32_bf16(a, b, c, 0, 0, 0);
}

// async global->LDS, 16B per lane, LDS dest = wave-uniform base + lane*16
static __device__ __forceinline__ void gload_lds16(const float* g, float* l) {
    __builtin_amdgcn_global_load_lds(
        (const __attribute__((address_space(1))) unsigned int*)(g),
        (__attribute__((address_space(3))) unsigned int*)(l), 16, 0, 0);
}

// ===================== Kernel P: prepack weights -> bf16 fragment-layout images =====================
__global__ __launch_bounds__(256) void prepack_kernel(
    const float* __restrict__ w_in,
    const float* __restrict__ wd0, const float* __restrict__ wp0,
    const float* __restrict__ wd1, const float* __restrict__ wp1,
    const float* __restrict__ wd2, const float* __restrict__ wp2,
    unsigned short* __restrict__ wk)
{
    int idx = blockIdx.x * 256 + threadIdx.x;
    if (idx >= 1024 + 3 * 16384) return;
    if (idx < 1024) {
        int c = idx >> 4, a = idx & 15;
        float wv = 0.f;
        if (a <= 8) {
            wv = w_in[c * 17 + 8 + a];
            if (a > 0) wv += w_in[c * 17 + 8 - a];
        }
        wk[idx] = f2bf(wv);
    } else {
        int i2 = idx - 1024;
        int s = i2 >> 14;
        int r = i2 & 16383;
        const float* wd = s == 0 ? wd0 : (s == 1 ? wd1 : wd2);
        const float* wp = s == 0 ? wp0 : (s == 1 ? wp1 : wp2);
        unsigned short v;
        if (r < 12288) {
            int c = r / 192, k = r - c * 192;
            int tap = k >> 6, ci = k & 63;
            v = f2bf(wd[c * 192 + ci * 3 + tap]);
        } else {
            v = f2bf(wp[r - 12288]);
        }
        wk[idx] = v;
    }
}

// ===================== Kernel A: MFMA Gram-band strip, async-LDS pipelined =====================
// Block: 256 thr (4 waves), RB=64 output rows, 80 staged rows. X staged f32 in LDS via
// global_load_lds (pre-swizzled source: 16B slot s of row r holds global slot s^(r&7)),
// double-buffered over K in 4 chunks of 64 f32, raw s_barrier + counted vmcnt(5).
#define RB 64
#define DBP 33            // dotbuf row pitch (f32) -> conflict-free
#define CHUNKF 64         // f32 per chunk per row
#define XROWS 80
#define XBUF_F (XROWS * CHUNKF)    // 5120 f32 = 20 KB per buffer

__global__ __launch_bounds__(256, 3) void strip_kernel(
    const float* __restrict__ feat0, const float* __restrict__ mask0,
    const float* __restrict__ feat1, const float* __restrict__ mask1,
    unsigned short* __restrict__ s16g)     // [2*B][T][16] bf16, slots 0..8 = bands, 9..15 = 0
{
    __shared__ float xbuf[2 * XBUF_F];           // 40 KB double buffer
    __shared__ float dotbuf[4 * 16 * DBP];       // per-wave 16x32 raw dots
    __shared__ float scl[80];
    __shared__ float msk[80];
    __shared__ float sdh[8];                     // halo self-dots rows 64..71

    int bid0 = blockIdx.x;                        // 4096 = 2*B*(T/RB)
    int bid  = (bid0 & 7) * 512 + (bid0 >> 3);    // XCD-chunked bijective swizzle
    int tile = bid & 63;
    int b    = (bid >> 6) & 31;
    int mod  = bid >> 11;
    int mb   = mod * B_ + b;
    const float* feat = mod ? feat1 : feat0;
    const float* mask = mod ? mask1 : mask0;
    int t0 = tile * RB;
    int tid = threadIdx.x;
    int w = tid >> 6, lane = tid & 63;
    int l15 = lane & 15, lg = lane >> 4;

    if (tid < 80) {
        int tg = t0 + tid;
        msk[tid] = (tg < T_) ? mask[(size_t)b * T_ + tg] : 0.f;
    }

    const float* fb = feat + (size_t)b * T_ * D_;

    // ---- async stage of one K-chunk (5 x 1KB per wave), source pre-swizzled
    auto stage_chunk = [&](int ct, int bf) {
        #pragma unroll
        for (int i = 0; i < 5; ++i) {
            int gi = w * 5 + i;
            int row = gi * 4 + (lane >> 4);
            int tg = t0 + row; if (tg >= T_) tg = 0;     // clamped rows are mask-zeroed later
            const float* gp = fb + (size_t)tg * D_ + ct * CHUNKF
                              + (((lane & 15) ^ (row & 7)) << 2);
            gload_lds16(gp, xbuf + bf * XBUF_F + gi * 256);
        }
    };

    int rA = w * 16 + l15;
    int rB = rA + 16;
    int a7 = rA & 7, b7 = rB & 7;
    int rh = 64 + w * 2 + (lane >> 5);           // halo row for this half-wave
    int l5 = lane & 31;
    int gh = l5 >> 1, he = (l5 & 1) * 2, h7 = rh & 7;

    f32x4 acc0 = {0.f, 0.f, 0.f, 0.f}, acc1 = {0.f, 0.f, 0.f, 0.f};
    float acc_h = 0.f;

    auto compute_chunk = [&](const float* xb) {
        const float* pa = xb + rA * 64;
        const float* pb = xb + rB * 64;
        #pragma unroll
        for (int q = 0; q < 2; ++q) {
            int g0 = q * 8 + lg * 2;
            float4 a0 = *(const float4*)(pa + ((g0 ^ a7) << 2));
            float4 a1 = *(const float4*)(pa + (((g0 + 1) ^ a7) << 2));
            float4 b0 = *(const float4*)(pb + ((g0 ^ b7) << 2));
            float4 b1 = *(const float4*)(pb + (((g0 + 1) ^ b7) << 2));
            bfrag av, bv;
            av[0] = (short)f2bf(a0.x); av[1] = (short)f2bf(a0.y);
            av[2] = (short)f2bf(a0.z); av[3] = (short)f2bf(a0.w);
            av[4] = (short)f2bf(a1.x); av[5] = (short)f2bf(a1.y);
            av[6] = (short)f2bf(a1.z); av[7] = (short)f2bf(a1.w);
            bv[0] = (short)f2bf(b0.x); bv[1] = (short)f2bf(b0.y);
            bv[2] = (short)f2bf(b0.z); bv[3] = (short)f2bf(b0.w);
            bv[4] = (short)f2bf(b1.x); bv[5] = (short)f2bf(b1.y);
            bv[6] = (short)f2bf(b1.z); bv[7] = (short)f2bf(b1.w);
            acc0 = mfma_bf16(av, av, acc0);
            acc1 = mfma_bf16(av, bv, acc1);
        }
        // halo self-dot partial (rows 64..71), bf16-rounded for consistency
        const float* hp = xb + rh * 64 + ((gh ^ h7) << 2) + he;
        float h0 = bf2f(f2bf(hp[0]));
        float h1 = bf2f(f2bf(hp[1]));
        acc_h += h0 * h0 + h1 * h1;
    };

    // ---- pipeline: stage 0,1 | {wait, bar, compute c, bar, stage c+2}
    stage_chunk(0, 0);
    stage_chunk(1, 1);

    asm volatile("s_waitcnt vmcnt(5)" ::: "memory");
    __builtin_amdgcn_sched_barrier(0);
    __builtin_amdgcn_s_barrier();
    compute_chunk(xbuf);
    asm volatile("s_waitcnt lgkmcnt(0)" ::: "memory");
    __builtin_amdgcn_sched_barrier(0);
    __builtin_amdgcn_s_barrier();
    stage_chunk(2, 0);

    asm volatile("s_waitcnt vmcnt(5)" ::: "memory");
    __builtin_amdgcn_sched_barrier(0);
    __builtin_amdgcn_s_barrier();
    compute_chunk(xbuf + XBUF_F);
    asm volatile("s_waitcnt lgkmcnt(0)" ::: "memory");
    __builtin_amdgcn_sched_barrier(0);
    __builtin_amdgcn_s_barrier();
    stage_chunk(3, 1);

    asm volatile("s_waitcnt vmcnt(5)" ::: "memory");
    __builtin_amdgcn_sched_barrier(0);
    __builtin_amdgcn_s_barrier();
    compute_chunk(xbuf);
    asm volatile("s_waitcnt lgkmcnt(0)" ::: "memory");
    __builtin_amdgcn_sched_barrier(0);
    __builtin_amdgcn_s_barrier();

    asm volatile("s_waitcnt vmcnt(0)" ::: "memory");
    __builtin_amdgcn_sched_barrier(0);
    __builtin_amdgcn_s_barrier();
    compute_chunk(xbuf + XBUF_F);

    // ---- publish dots + halo self-dots
    #pragma unroll
    for (int r = 0; r < 4; ++r) {
        dotbuf[w * 16 * DBP + (lg * 4 + r) * DBP + l15] = acc0[r];
        dotbuf[w * 16 * DBP + (lg * 4 + r) * DBP + 16 + l15] = acc1[r];
    }
    acc_h += __shfl_xor(acc_h, 1);
    acc_h += __shfl_xor(acc_h, 2);
    acc_h += __shfl_xor(acc_h, 4);
    acc_h += __shfl_xor(acc_h, 8);
    acc_h += __shfl_xor(acc_h, 16);
    if (l5 == 0) sdh[rh - 64] = acc_h;
    __syncthreads();

    // ---- scl[t] = m / (m*sqrt(selfdot) + eps), t in [0,72)
    if (tid < 72) {
        float sd = (tid < 64) ? dotbuf[(tid >> 4) * 16 * DBP + (tid & 15) * DBP + (tid & 15)]
                              : sdh[tid - 64];
        float m = msk[tid];
        float nm = m * sqrtf(sd);
        scl[tid] = m / (nm + EPSN);
    }
    __syncthreads();

    // ---- band extraction + bf16 pack (threads 0..63 = rows)
    if (tid < RB) {
        int t = tid, wq = t >> 4, r = t & 15;
        float m_t = msk[t], sc_t = scl[t];
        ushort8_t o0, o1;
        #pragma unroll
        for (int e = 0; e < 8; ++e) { o0[e] = 0; o1[e] = 0; }
        #pragma unroll
        for (int a = 0; a <= 8; ++a) {
            float dot = dotbuf[wq * 16 * DBP + r * DBP + r + a];
            float dn = dot * sc_t * scl[t + a];
            float s = (dn - (a == 0 ? DS_ : 0.f) + 1.f) * 0.5f * m_t * msk[t + a];
            if (a < 8) o0[a] = f2bf(s); else o1[0] = f2bf(s);
        }
        unsigned short* dst = s16g + ((size_t)mb * T_ + t0 + t) * 16;
        *(ushort8_t*)dst = o0;
        *(ushort8_t*)(dst + 8) = o1;
    }
}

// ===================== Kernel B: MFMA conv stack + masked GAP partials =====================
#define TT 128
#define G_ 16
#define WB 160            // TT + 2*G_
#define SBP 24            // sbuf pitch (48B rows: 16B-aligned, conflict-free)
#define OFF_BUFA 8192
#define OFF_BUFB 28672
#define OFF_MLD  49664
#define OFF_RED  50176
#define SMEM_TOT (OFF_RED + 1024)

// swizzled ushort index: 16B slot su (0..7) of row, XOR'd by row&7; off = ushort offset in slot
static __device__ __forceinline__ int swzi(int row, int su, int off) {
    return row * 64 + ((su ^ (row & 7)) << 3) + off;
}

template<int DIL>
static __device__ __forceinline__ void conv_stage(
    const unsigned short* __restrict__ wdg, const unsigned short* __restrict__ wpg,
    unsigned short* __restrict__ bufIn, unsigned short* __restrict__ bufOut,
    const float* __restrict__ b_d, const float* __restrict__ b_p,
    int t0, int l15, int lg, int mt0, int wn)
{
    // ---- dilated 3-tap conv as K=192 GEMM (k = tap*64 + ci), bufIn -> bufOut
    {
        bfrag ad[2][6];
        float bd[2][4];
        #pragma unroll
        for (int m = 0; m < 2; ++m) {
            int row = (mt0 + m) * 16 + l15;
            #pragma unroll
            for (int ks = 0; ks < 6; ++ks) {
                int tap = ks >> 1, half = ks & 1;
                ad[m][ks] = *(const bfrag*)(wdg + row * 192 + tap * 64 + half * 32 + lg * 8);
            }
            #pragma unroll
            for (int r = 0; r < 4; ++r) bd[m][r] = b_d[(mt0 + m) * 16 + lg * 4 + r];
        }
        for (int nt = wn * 5; nt < wn * 5 + 5; ++nt) {
            int j = nt * 16 + l15;
            f32x4 acc0 = {0.f, 0.f, 0.f, 0.f}, acc1 = {0.f, 0.f, 0.f, 0.f};
            #pragma unroll
            for (int ks = 0; ks < 6; ++ks) {
                int tap = ks >> 1, half = ks & 1;
                int brow = j + (tap - 1) * DIL;
                bfrag bv = *(const bfrag*)(bufIn + swzi(brow, half * 4 + lg, 0));
                acc0 = mfma_bf16(ad[0][ks], bv, acc0);
                acc1 = mfma_bf16(ad[1][ks], bv, acc1);
            }
            int tg = t0 - G_ + j;
            bool valid = (tg >= 0 && tg < T_);
            #pragma unroll
            for (int m = 0; m < 2; ++m) {
                f32x4 acc = m ? acc1 : acc0;
                ushort4_t pk;
                #pragma unroll
                for (int r = 0; r < 4; ++r) {
                    float v = acc[r] + bd[m][r];
                    v = valid ? fmaxf(v, 0.f) : 0.f;
                    pk[r] = f2bf(v);
                }
                *(ushort4_t*)(bufOut + swzi(j, (mt0 + m) * 2 + (lg >> 1), (lg & 1) * 4)) = pk;
            }
        }
    }
    __syncthreads();

    // ---- pointwise conv as K=64 GEMM, bufOut -> bufIn
    {
        bfrag ap[2][2];
        float bpv[2][4];
        #pragma unroll
        for (int m = 0; m < 2; ++m) {
            int row = (mt0 + m) * 16 + l15;
            #pragma unroll
            for (int half = 0; half < 2; ++half)
                ap[m][half] = *(const bfrag*)(wpg + row * 64 + half * 32 + lg * 8);
            #pragma unroll
            for (int r = 0; r < 4; ++r) bpv[m][r] = b_p[(mt0 + m) * 16 + lg * 4 + r];
        }
        for (int nt = wn * 5; nt < wn * 5 + 5; ++nt) {
            int j = nt * 16 + l15;
            f32x4 acc0 = {0.f, 0.f, 0.f, 0.f}, acc1 = {0.f, 0.f, 0.f, 0.f};
            #pragma unroll
            for (int half = 0; half < 2; ++half) {
                bfrag bv = *(const bfrag*)(bufOut + swzi(j, half * 4 + lg, 0));
                acc0 = mfma_bf16(ap[0][half], bv, acc0);
                acc1 = mfma_bf16(ap[1][half], bv, acc1);
            }
            int tg = t0 - G_ + j;
            bool valid = (tg >= 0 && tg < T_);
            #pragma unroll
            for (int m = 0; m < 2; ++m) {
                f32x4 acc = m ? acc1 : acc0;
                ushort4_t pk;
                #pragma unroll
                for (int r = 0; r < 4; ++r) {
                    float v = acc[r] + bpv[m][r];
                    v = valid ? fmaxf(v, 0.f) : 0.f;
                    pk[r] = f2bf(v);
                }
                *(ushort4_t*)(bufIn + swzi(j, (mt0 + m) * 2 + (lg >> 1), (lg & 1) * 4)) = pk;
            }
        }
    }
    __syncthreads();
}

__global__ __launch_bounds__(256, 3) void conv_mfma_kernel(
    const unsigned short* __restrict__ s16g,
    const float* __restrict__ mask0, const float* __restrict__ mask1,
    const unsigned short* __restrict__ wk,
    const float* __restrict__ b_in,
    const float* __restrict__ b_d1, const float* __restrict__ b_p1,
    const float* __restrict__ b_d2, const float* __restrict__ b_p2,
    const float* __restrict__ b_d3, const float* __restrict__ b_p3,
    float* __restrict__ z_part)        // [2*B][32][64]
{
    __shared__ __align__(16) char smem[SMEM_TOT];
    unsigned short* sbuf = (unsigned short*)smem;                 // [WB][SBP]
    unsigned short* bufA = (unsigned short*)(smem + OFF_BUFA);
    unsigned short* bufB = (unsigned short*)(smem + OFF_BUFB);
    float* mld = (float*)(smem + OFF_MLD);                        // [TT]
    float* red = (float*)(smem + OFF_RED);                        // [4][64]

    int bid  = blockIdx.x;                             // 2*B*32 = 2048
    int tile = bid & 31;
    int b    = (bid >> 5) & 31;
    int mod  = bid >> 10;
    int mb   = mod * B_ + b;
    const float* mask = mod ? mask1 : mask0;
    int t0  = tile * TT;
    int tid = threadIdx.x;
    int lane = tid & 63;
    int w = tid >> 6;
    int l15 = lane & 15, lg = lane >> 4;
    int wm = w >> 1, wn = w & 1;
    int mt0 = wm * 2;

    const unsigned short* weff_g = wk;

    // ---- stage s16 tile (with t-bounds zero fill) + mask
    {
        const unsigned short* srow = s16g + (size_t)mb * T_ * 16;
        for (int ch = tid; ch < WB * 2; ch += 256) {
            int j = ch >> 1, q = ch & 1;
            int t = t0 - G_ + j;
            ushort8_t v = {0, 0, 0, 0, 0, 0, 0, 0};
            if (t >= 0 && t < T_) v = *(const ushort8_t*)(srow + (size_t)t * 16 + q * 8);
            *(ushort8_t*)(sbuf + j * SBP + q * 8) = v;
        }
        if (tid < TT) {
            int tg = t0 + tid;
            mld[tid] = (tg < T_) ? mask[(size_t)b * T_ + tg] : 0.f;
        }
    }
    __syncthreads();

    // ---- in-conv (K=9 padded into one masked K=32 MFMA step) -> bufA
    {
        int lg2 = lg & 1;
        bfrag a_in[2];
        float bi[2][4];
        #pragma unroll
        for (int m = 0; m < 2; ++m) {
            int row = (mt0 + m) * 16 + l15;
            a_in[m] = *(const bfrag*)(weff_g + row * 16 + lg2 * 8);
            #pragma unroll
            for (int r = 0; r < 4; ++r) bi[m][r] = b_in[(mt0 + m) * 16 + lg * 4 + r];
        }
        for (int nt = wn * 5; nt < wn * 5 + 5; ++nt) {
            int j = nt * 16 + l15;
            bfrag bv = {0, 0, 0, 0, 0, 0, 0, 0};
            if (lg < 2) bv = *(const bfrag*)(sbuf + j * SBP + lg * 8);
            f32x4 acc0 = {0.f, 0.f, 0.f, 0.f}, acc1 = {0.f, 0.f, 0.f, 0.f};
            acc0 = mfma_bf16(a_in[0], bv, acc0);
            acc1 = mfma_bf16(a_in[1], bv, acc1);
            int tg = t0 - G_ + j;
            bool valid = (tg >= 0 && tg < T_);
            #pragma unroll
            for (int m = 0; m < 2; ++m) {
                f32x4 acc = m ? acc1 : acc0;
                ushort4_t pk;
                #pragma unroll
                for (int r = 0; r < 4; ++r) {
                    float v = acc[r] + bi[m][r];
                    v = valid ? fmaxf(v, 0.f) : 0.f;
                    pk[r] = f2bf(v);
                }
                *(ushort4_t*)(bufA + swzi(j, (mt0 + m) * 2 + (lg >> 1), (lg & 1) * 4)) = pk;
            }
        }
    }
    __syncthreads();

    conv_stage<1>(wk + 1024,             wk + 1024 + 12288,             bufA, bufB, b_d1, b_p1, t0, l15, lg, mt0, wn);
    conv_stage<2>(wk + 1024 + 16384,     wk + 1024 + 16384 + 12288,     bufA, bufB, b_d2, b_p2, t0, l15, lg, mt0, wn);
    conv_stage<4>(wk + 1024 + 2 * 16384, wk + 1024 + 2 * 16384 + 12288, bufA, bufB, b_d3, b_p3, t0, l15, lg, mt0, wn);

    // ---- masked GAP partial over this tile's 128 cols (j in [G_, G_+TT))
    {
        int c = tid & 63, g = tid >> 6;
        float acc = 0.f;
        #pragma unroll 4
        for (int i = 0; i < 32; ++i) {
            int jj = g * 32 + i;
            int r = G_ + jj;
            acc += bf2f(bufA[swzi(r, c >> 3, c & 7)]) * mld[jj];
        }
        red[g * 64 + c] = acc;
    }
    __syncthreads();
    if (tid < 64) {
        float z = red[tid] + red[64 + tid] + red[128 + tid] + red[192 + tid];
        z_part[((size_t)mb * 32 + tile) * 64 + tid] = z;
    }
}

// ===================== Kernel C: GAP divide + LayerNorm + gates =====================
__global__ __launch_bounds__(128) void gates_kernel(
    const float* __restrict__ z_part,
    const float* __restrict__ mask0, const float* __restrict__ mask1,
    const float* __restrict__ ln_g, const float* __restrict__ ln_b,
    const float* __restrict__ mha_w1, const float* __restrict__ mha_b1,
    const float* __restrict__ mha_w2, const float* __restrict__ mha_b2,
    const float* __restrict__ ffn_w1, const float* __restrict__ ffn_b1,
    const float* __restrict__ ffn_w2, const float* __restrict__ ffn_b2,
    float* __restrict__ out)
{
    __shared__ float fn[128];
    __shared__ float red[4];
    __shared__ float msum[2];
    int b = blockIdx.x, tid = threadIdx.x;
    int mod = tid >> 6, c = tid & 63;

    float z = 0.f;
    for (int tl = 0; tl < 32; ++tl)
        z += z_part[((size_t)(mod * B_ + b) * 32 + tl) * 64 + c];

    const float* mk = mod ? mask1 : mask0;
    float ms = 0.f;
    for (int t = c; t < T_; t += 64) ms += mk[(size_t)b * T_ + t];
    #pragma unroll
    for (int o = 32; o > 0; o >>= 1) ms += __shfl_xor(ms, o);
    if (c == 0) msum[mod] = ms;
    __syncthreads();

    float fv = z / (msum[mod] + EPSG);
    float s1 = fv, s2 = fv * fv;
    #pragma unroll
    for (int o = 32; o > 0; o >>= 1) { s1 += __shfl_xor(s1, o); s2 += __shfl_xor(s2, o); }
    if (c == 0) { red[mod * 2] = s1; red[mod * 2 + 1] = s2; }
    __syncthreads();

    float mu  = (red[0] + red[2]) * (1.0f / 128.0f);
    float ex2 = (red[1] + red[3]) * (1.0f / 128.0f);
    float var = ex2 - mu * mu;
    float fnv = (fv - mu) * rsqrtf(var + EPSL) * ln_g[tid] + ln_b[tid];
    fn[tid] = fnv;
    __syncthreads();

    const float* W1 = mod ? ffn_w1 : mha_w1;
    const float* B1 = mod ? ffn_b1 : mha_b1;
    const float* W2 = mod ? ffn_w2 : mha_w2;
    const float* B2 = mod ? ffn_b2 : mha_b2;
    float r = B1[c];
    for (int i = 0; i < 128; ++i) r += fn[i] * W1[i * 64 + c];
    r = fmaxf(r, 0.f);
    float g = r * W2[c];
    #pragma unroll
    for (int o = 32; o > 0; o >>= 1) g += __shfl_xor(g, o);
    if (c == 0) {
        g += B2[0];
        out[mod * B_ + b] = mod ? tanhf(g) : 1.0f / (1.0f + expf(-g));
    }
}

// ===================== launch =====================
extern "C" void kernel_launch(void* const* d_in, const int* in_sizes, int n_in,
                              void* d_out, int out_size, void* d_ws, size_t ws_size,
                              hipStream_t stream) {
    const float* video_feat = (const float*)d_in[0];
    const float* audio_feat = (const float*)d_in[1];
    const float* video_mask = (const float*)d_in[2];
    const float* audio_mask = (const float*)d_in[3];
    const float* w_in = (const float*)d_in[4];
    const float* b_in = (const float*)d_in[5];
    const float* w_d1 = (const float*)d_in[6];
    const float* b_d1 = (const float*)d_in[7];
    const float* w_p1 = (const float*)d_in[8];
    const float* b_p1 = (const float*)d_in[9];
    const float* w_d2 = (const float*)d_in[10];
    const float* b_d2 = (const float*)d_in[11];
    const float* w_p2 = (const float*)d_in[12];
    const float* b_p2 = (const float*)d_in[13];
    const float* w_d3 = (const float*)d_in[14];
    const float* b_d3 = (const float*)d_in[15];
    const float* w_p3 = (const float*)d_in[16];
    const float* b_p3 = (const float*)d_in[17];
    const float* ln_g = (const float*)d_in[18];
    const float* ln_b = (const float*)d_in[19];
    const float* mha_w1 = (const float*)d_in[20];
    const float* mha_b1 = (const float*)d_in[21];
    const float* mha_w2 = (const float*)d_in[22];
    const float* mha_b2 = (const float*)d_in[23];
    const float* ffn_w1 = (const float*)d_in[24];
    const float* ffn_b1 = (const float*)d_in[25];
    const float* ffn_w2 = (const float*)d_in[26];
    const float* ffn_b2 = (const float*)d_in[27];

    unsigned short* s16g = (unsigned short*)d_ws;                          // 2*B*T*16 bf16 = 8.39 MB
    float* z_part = (float*)((char*)d_ws + (size_t)2 * B_ * T_ * 16 * 2);  // 2*B*32*64 f32 = 512 KB
    unsigned short* wk = (unsigned short*)((char*)z_part + (size_t)2 * B_ * 32 * 64 * 4);  // 100 KB

    prepack_kernel<<<dim3(196), dim3(256), 0, stream>>>(
        w_in, w_d1, w_p1, w_d2, w_p2, w_d3, w_p3, wk);

    strip_kernel<<<dim3(2 * B_ * (T_ / RB)), dim3(256), 0, stream>>>(
        audio_feat, audio_mask, video_feat, video_mask, s16g);

    conv_mfma_kernel<<<dim3(2 * B_ * (T_ / TT)), dim3(256), 0, stream>>>(
        s16g, audio_mask, video_mask, wk, b_in,
        b_d1, b_p1, b_d2, b_p2, b_d3, b_p3, z_part);

    gates_kernel<<<dim3(B_), dim3(128), 0, stream>>>(
        z_part, audio_mask, video_mask, ln_g, ln_b,
        mha_w1, mha_b1, mha_w2, mha_b2, ffn_w1, ffn_b1, ffn_w2, ffn_b2,
        (float*)d_out);
}